// Round 2
// 415.699 us; speedup vs baseline: 1.2698x; 1.2698x over previous
//
#include <hip/hip_runtime.h>
#include <stdint.h>

// GNN: 2x GraphConv (norm='both') + attention gate + mean pooling + classifier.
// Round-9 model (resubmit after infra flake): fat1's 3.2M global atomics ran at
// ~16.8 G/s (32B fabric write-through each) = 190us wall. Replace
// histogram+rank-capture with an atomic-free bucket partition (dst>>8 / src>>8,
// 391 buckets) + per-bucket LDS counting sort that emits rowptr/col/norms
// directly. Kills fat1, fat2, norm, scan1-3, zero. gemm1 fuses the norm_out
// scale (no raw+rescale pass).

#define N_NODES   100000
#define N_EDGES   1600000
#define N_GRAPHS  64
#define IN_DIM    128
#define HID       64
#define N_CLASSES 10

#define NBUCK     391       // ceil(100000/256) buckets of 256 nodes
#define P1B       196       // partition chunk blocks
#define EPB       8192      // edges per chunk block (196*8192 >= 1.6M)
#define GB_BLOCKS 391       // ceil(100000/256)
#define GEMM_BLOCKS 782     // ceil(100000/128)
#define WS_NEED   33885952u

__device__ __forceinline__ float bf2f(unsigned short u) {
  unsigned int v = ((unsigned int)u) << 16;
  float f;
  __builtin_memcpy(&f, &v, 4);
  return f;
}

__device__ __forceinline__ unsigned short f2bf(float f) {
  unsigned int x;
  __builtin_memcpy(&x, &f, 4);
  unsigned int lsb = (x >> 16) & 1u;
  x += 0x7fffu + lsb;  // round-to-nearest-even
  return (unsigned short)(x >> 16);
}

__device__ __forceinline__ void unpack_bf2(unsigned int u, float& lo, float& hi) {
  unsigned int a = u << 16;
  unsigned int b = u & 0xffff0000u;
  __builtin_memcpy(&lo, &a, 4);
  __builtin_memcpy(&hi, &b, 4);
}

// mode: 1 = tensors are bf16, 0 = tensors are fp32
__device__ __forceinline__ float ldf(const void* p, int i, int mode) {
  return mode ? bf2f(((const unsigned short*)p)[i]) : ((const float*)p)[i];
}

// ---------------- dtype probe ----------------
__global__ __launch_bounds__(256) void probe_kernel(const unsigned short* __restrict__ xu,
                                                    int* __restrict__ flag) {
  int tid = (int)threadIdx.x;
  unsigned u = xu[2 * tid];
  int e = (int)((u >> 7) & 0xFF);
  int ok = (e >= 110 && e <= 132) ? 1 : 0;
  unsigned long long m = __ballot(ok);
  __shared__ int cnt[4];
  if ((tid & 63) == 0) cnt[tid >> 6] = __popcll(m);
  __syncthreads();
  if (tid == 0) {
    flag[0] = (cnt[0] + cnt[1] + cnt[2] + cnt[3] > 128) ? 1 : 0;
    flag[1] = 1;
  }
}

// ---------------- fallback (ws too small): deterministic zero output ----------
__global__ __launch_bounds__(256) void fallback_kernel(unsigned short* __restrict__ out,
                                                       int n) {
  int i = blockIdx.x * 256 + threadIdx.x;
  if (i < n) out[i] = 0;
}

// ---------------- params -> fp32 ----------------
__global__ __launch_bounds__(256) void wcvt_kernel(
    const void* __restrict__ W1, const void* __restrict__ W2,
    const void* __restrict__ b1, const void* __restrict__ b2,
    const void* __restrict__ attnW, const void* __restrict__ attnb,
    const void* __restrict__ clsW, const void* __restrict__ clsb,
    float* __restrict__ Wf1, float* __restrict__ Wf2,
    float* __restrict__ b1f, float* __restrict__ b2f,
    float* __restrict__ attnWf, float* __restrict__ attnbf,
    float* __restrict__ clsWf, float* __restrict__ clsbf,
    const int* __restrict__ flag) {
  int mode = flag[0];
  int i = blockIdx.x * 256 + threadIdx.x;
  if (i < IN_DIM * HID) Wf1[i] = ldf(W1, i, mode);
  if (i < HID * HID)    Wf2[i] = ldf(W2, i, mode);
  if (i < HID) {
    b1f[i] = ldf(b1, i, mode);
    b2f[i] = ldf(b2, i, mode);
    attnWf[i] = ldf(attnW, i, mode);
  }
  if (i == 0) attnbf[0] = ldf(attnb, 0, mode);
  if (i < HID * N_CLASSES) clsWf[i] = ldf(clsW, i, mode);
  if (i < N_CLASSES) clsbf[i] = ldf(clsb, i, mode);
}

// =============== P1: per-chunk bucket histograms (dst & src) | gbound ========
// Blocks [0,P1B): LDS histogram of dst>>8 and src>>8 for an 8192-edge chunk,
// written densely to blkhistD/S[blk][bucket]. No global atomics.
// Blocks [P1B, P1B+GB_BLOCKS): graph boundaries from sorted gid.
__global__ __launch_bounds__(256) void part_count_kernel(
    const int* __restrict__ ei, int* __restrict__ blkhistD,
    int* __restrict__ blkhistS,
    const int* __restrict__ gid, int* __restrict__ gstart) {
  int b = (int)blockIdx.x;
  int t = (int)threadIdx.x;
  if (b < P1B) {
    __shared__ int hD[NBUCK];
    __shared__ int hS[NBUCK];
    for (int i = t; i < NBUCK; i += 256) { hD[i] = 0; hS[i] = 0; }
    __syncthreads();
    int base_e = b * EPB;
    for (int s = 0; s < EPB / 1024; ++s) {
      int e4 = base_e + s * 1024 + t * 4;
      if (e4 < N_EDGES) {
        int4 s4 = *(const int4*)(ei + e4);
        int4 d4 = *(const int4*)(ei + N_EDGES + e4);
        int ss[4] = {s4.x, s4.y, s4.z, s4.w};
        int dd[4] = {d4.x, d4.y, d4.z, d4.w};
#pragma unroll
        for (int j = 0; j < 4; ++j) {
          if ((unsigned)ss[j] < N_NODES) atomicAdd(&hS[ss[j] >> 8], 1);
          if ((unsigned)dd[j] < N_NODES) atomicAdd(&hD[dd[j] >> 8], 1);
        }
      }
    }
    __syncthreads();
    for (int i = t; i < NBUCK; i += 256) {
      blkhistD[b * NBUCK + i] = hD[i];
      blkhistS[b * NBUCK + i] = hS[i];
    }
  } else {
    // ---- gbound part ----
    int bb = b - P1B;
    int n = bb * 256 + t;
    if (n >= N_NODES) return;
    int gc = gid[n] & (N_GRAPHS - 1);
    if (n == 0) {
      for (int g = 0; g <= gc; ++g) gstart[g] = 0;
    } else {
      int gp = gid[n - 1] & (N_GRAPHS - 1);
      for (int g = gp + 1; g <= gc; ++g) gstart[g] = n;
    }
    if (n == N_NODES - 1) {
      for (int g = gc + 1; g <= N_GRAPHS; ++g) gstart[g] = N_NODES;
    }
  }
}

// =============== P2: bucket totals scan + in-place per-block bases ===========
// block 0 handles D, block 1 handles S. hist[blk][u] is rewritten in place to
// the exclusive base offset for that (block, bucket). bstart[u] = bucket start.
__global__ __launch_bounds__(512) void bucket_scan_kernel(
    int* __restrict__ blkhistD, int* __restrict__ blkhistS,
    int* __restrict__ bstart_d, int* __restrict__ bstart_s) {
  int* hist = (blockIdx.x == 0) ? blkhistD : blkhistS;
  int* bst  = (blockIdx.x == 0) ? bstart_d : bstart_s;
  int u = (int)threadIdx.x;
  int tot = 0;
  if (u < NBUCK) {
    for (int blk = 0; blk < P1B; ++blk) tot += hist[blk * NBUCK + u];
  }
  __shared__ int smA[512];
  __shared__ int smB[512];
  smA[u] = tot;
  __syncthreads();
  int* a = smA;
  int* bq = smB;
  for (int off = 1; off < 512; off <<= 1) {
    int v = a[u];
    if (u >= off) v += a[u - off];
    bq[u] = v;
    __syncthreads();
    int* tmp = a; a = bq; bq = tmp;
  }
  int excl = a[u] - tot;
  if (u <= NBUCK) bst[u] = excl;  // u==NBUCK: tot==0 -> excl == total
  if (u < NBUCK) {
    int off2 = excl;
    for (int blk = 0; blk < P1B; ++blk) {
      int h = hist[blk * NBUCK + u];
      hist[blk * NBUCK + u] = off2;
      off2 += h;
    }
  }
}

// =============== P3: scatter edges into bucket-partitioned arrays ============
// LDS cursors seeded from per-(block,bucket) bases -> each block writes a
// private slice of each bucket region. No global atomics, no cross-block races.
__global__ __launch_bounds__(256) void part_scatter_kernel(
    const int* __restrict__ ei, const int* __restrict__ blkbaseD,
    const int* __restrict__ blkbaseS,
    int2* __restrict__ edst, int* __restrict__ esrc) {
  __shared__ int cD[NBUCK];
  __shared__ int cS[NBUCK];
  int b = (int)blockIdx.x;
  int t = (int)threadIdx.x;
  for (int i = t; i < NBUCK; i += 256) {
    cD[i] = blkbaseD[b * NBUCK + i];
    cS[i] = blkbaseS[b * NBUCK + i];
  }
  __syncthreads();
  int base_e = b * EPB;
  for (int s = 0; s < EPB / 1024; ++s) {
    int e4 = base_e + s * 1024 + t * 4;
    if (e4 < N_EDGES) {
      int4 s4 = *(const int4*)(ei + e4);
      int4 d4 = *(const int4*)(ei + N_EDGES + e4);
      int ss[4] = {s4.x, s4.y, s4.z, s4.w};
      int dd[4] = {d4.x, d4.y, d4.z, d4.w};
#pragma unroll
      for (int j = 0; j < 4; ++j) {
        if ((unsigned)ss[j] < N_NODES) {
          int slot = atomicAdd(&cS[ss[j] >> 8], 1);
          esrc[slot] = ss[j];
        }
        if ((unsigned)dd[j] < N_NODES) {
          int slot = atomicAdd(&cD[dd[j] >> 8], 1);
          edst[slot] = make_int2(ss[j], dd[j]);
        }
      }
    }
  }
}

// =============== P4: per-bucket counting sort -> rowptr/col/norms ============
// Blocks [0,NBUCK): dst side -> rowptr, col, norm_in.
// Blocks [NBUCK,2*NBUCK): src side -> norm_out.
__global__ __launch_bounds__(256) void csr_kernel(
    const int2* __restrict__ edst, const int* __restrict__ esrc,
    const int* __restrict__ bstart_d, const int* __restrict__ bstart_s,
    int* __restrict__ rowptr, int* __restrict__ colx,
    float* __restrict__ norm_in, float* __restrict__ norm_out) {
  __shared__ int lc[256];
  __shared__ int smA[256];
  __shared__ int smB[256];
  int b = (int)blockIdx.x;
  int t = (int)threadIdx.x;
  if (b < NBUCK) {
    int node0 = b << 8;
    int base = bstart_d[b];
    int end  = bstart_d[b + 1];
    lc[t] = 0;
    __syncthreads();
    for (int i = base + t; i < end; i += 256) {
      int2 p = edst[i];
      atomicAdd(&lc[p.y - node0], 1);
    }
    __syncthreads();
    int my = lc[t];
    smA[t] = my;
    __syncthreads();
    int* a = smA;
    int* bq = smB;
    for (int off = 1; off < 256; off <<= 1) {
      int v = a[t];
      if (t >= off) v += a[t - off];
      bq[t] = v;
      __syncthreads();
      int* tmp = a; a = bq; bq = tmp;
    }
    int excl = a[t] - my;
    int n = node0 + t;
    if (n <= N_NODES) rowptr[n] = base + excl;
    if (n < N_NODES) {
      int c = my < 1 ? 1 : my;
      norm_in[n] = rsqrtf((float)c);
    }
    __syncthreads();
    lc[t] = base + excl;  // per-node cursor
    __syncthreads();
    for (int i = base + t; i < end; i += 256) {
      int2 p = edst[i];
      int slot = atomicAdd(&lc[p.y - node0], 1);
      colx[slot] = p.x;
    }
  } else {
    int bb = b - NBUCK;
    int node0 = bb << 8;
    int base = bstart_s[bb];
    int end  = bstart_s[bb + 1];
    lc[t] = 0;
    __syncthreads();
    for (int i = base + t; i < end; i += 256) {
      atomicAdd(&lc[esrc[i] - node0], 1);
    }
    __syncthreads();
    int n = node0 + t;
    if (n < N_NODES) {
      int c = lc[t] < 1 ? 1 : lc[t];
      norm_out[n] = rsqrtf((float)c);
    }
  }
}

// ---------------- GEMM (with norm scaling): out = (A . Wf) * norm_out --------
template <int K>
__global__ __launch_bounds__(256) void gemm_kernel(const void* __restrict__ A,
                                                   const float* __restrict__ Wf,
                                                   const float* __restrict__ norm_out,
                                                   unsigned short* __restrict__ out,
                                                   const int* __restrict__ flag) {
  int mode = flag[0];
  int n = blockIdx.x * 128 + ((int)threadIdx.x & 127);
  int d0 = __builtin_amdgcn_readfirstlane((int)((threadIdx.x >> 7) << 5));
  if (n >= N_NODES) return;
  float acc[32];
#pragma unroll
  for (int i = 0; i < 32; ++i) acc[i] = 0.f;
  if (mode) {
    const unsigned short* xr = (const unsigned short*)A + (size_t)n * K;
    for (int k0 = 0; k0 < K; k0 += 8) {
      uint4 xv = *(const uint4*)(xr + k0);
      float xf[8];
      unpack_bf2(xv.x, xf[0], xf[1]);
      unpack_bf2(xv.y, xf[2], xf[3]);
      unpack_bf2(xv.z, xf[4], xf[5]);
      unpack_bf2(xv.w, xf[6], xf[7]);
#pragma unroll
      for (int j = 0; j < 8; ++j) {
        const float* wrow = Wf + (k0 + j) * HID + d0;
#pragma unroll
        for (int d = 0; d < 32; ++d) acc[d] += xf[j] * wrow[d];
      }
    }
  } else {
    const float* xr = (const float*)A + (size_t)n * K;
    for (int k0 = 0; k0 < K; k0 += 8) {
      float4 a0 = *(const float4*)(xr + k0);
      float4 a1 = *(const float4*)(xr + k0 + 4);
      float xf[8] = {a0.x, a0.y, a0.z, a0.w, a1.x, a1.y, a1.z, a1.w};
#pragma unroll
      for (int j = 0; j < 8; ++j) {
        const float* wrow = Wf + (k0 + j) * HID + d0;
#pragma unroll
        for (int d = 0; d < 32; ++d) acc[d] += xf[j] * wrow[d];
      }
    }
  }
  float s = norm_out[n];
  unsigned short* orow = out + (size_t)n * HID + d0;
#pragma unroll
  for (int d = 0; d < 32; ++d) orow[d] = f2bf(acc[d] * s);
}

// ---------------- SpMM gather core: 32 edges in flight per iteration ----------
__device__ __forceinline__ void spmm_gather(const unsigned short* __restrict__ hs,
                                            const int* __restrict__ col,
                                            int e0, int e1, int row_sel, int dim0,
                                            float acc[8]) {
  for (int e = e0; e < e1; e += 32) {
    uint4 v[4];
#pragma unroll
    for (int j = 0; j < 4; ++j) {
      v[j] = make_uint4(0u, 0u, 0u, 0u);
      int ee = e + (j << 3) + row_sel;
      if (ee < e1) {
        unsigned s = (unsigned)col[ee];
        if (s < N_NODES) v[j] = *(const uint4*)(hs + ((size_t)s << 6) + dim0);
      }
    }
#pragma unroll
    for (int j = 0; j < 4; ++j) {
      float lo, hi;
      unpack_bf2(v[j].x, lo, hi); acc[0] += lo; acc[1] += hi;
      unpack_bf2(v[j].y, lo, hi); acc[2] += lo; acc[3] += hi;
      unpack_bf2(v[j].z, lo, hi); acc[4] += lo; acc[5] += hi;
      unpack_bf2(v[j].w, lo, hi); acc[6] += lo; acc[7] += hi;
    }
  }
  // fold the 8 edge-groups: lanes sharing (lane&7) differ in bits 3..5
#pragma unroll
  for (int m = 8; m <= 32; m <<= 1) {
#pragma unroll
    for (int i = 0; i < 8; ++i) acc[i] += __shfl_xor(acc[i], m, 64);
  }
}

// ---------------- SpMM layer-1: wave per node ----------------
__global__ __launch_bounds__(256) void spmm_kernel(const unsigned short* __restrict__ hs,
                                                   const int* __restrict__ rowptr,
                                                   const int* __restrict__ col,
                                                   const float* __restrict__ norm_in,
                                                   const float* __restrict__ b1f,
                                                   unsigned short* __restrict__ out) {
  int n = (int)((blockIdx.x * 256 + threadIdx.x) >> 6);
  int lane = (int)threadIdx.x & 63;
  if (n >= N_NODES) return;
  int row_sel = lane >> 3;
  int dim0 = (lane & 7) << 3;
  int e0 = rowptr[n], e1 = rowptr[n + 1];
  if (e0 < 0) e0 = 0;
  if (e1 > N_EDGES) e1 = N_EDGES;
  float acc[8];
#pragma unroll
  for (int i = 0; i < 8; ++i) acc[i] = 0.f;
  spmm_gather(hs, col, e0, e1, row_sel, dim0, acc);
  if (row_sel == 0) {
    float nin = norm_in[n];
    unsigned int pk[4];
#pragma unroll
    for (int i = 0; i < 4; ++i) {
      float vlo = fmaxf(acc[2 * i] * nin + b1f[dim0 + 2 * i], 0.f);
      float vhi = fmaxf(acc[2 * i + 1] * nin + b1f[dim0 + 2 * i + 1], 0.f);
      pk[i] = (unsigned int)f2bf(vlo) | ((unsigned int)f2bf(vhi) << 16);
    }
    *(uint4*)(out + ((size_t)n << 6) + dim0) = make_uint4(pk[0], pk[1], pk[2], pk[3]);
  }
}

// ------- SpMM layer-2 fused with attention gate; writes gated bf16 rows -------
__global__ __launch_bounds__(256) void spmm_attn_kernel(
    const unsigned short* __restrict__ hs,
    const int* __restrict__ rowptr, const int* __restrict__ col,
    const float* __restrict__ norm_in, const float* __restrict__ b2f,
    const float* __restrict__ attnWf, const float* __restrict__ attnbf,
    void* __restrict__ out_base, unsigned short* __restrict__ gated,
    const int* __restrict__ flag) {
  int mode = flag[0];
  int n = (int)((blockIdx.x * 256 + threadIdx.x) >> 6);
  int lane = (int)threadIdx.x & 63;
  if (n >= N_NODES) return;
  int row_sel = lane >> 3;
  int dim0 = (lane & 7) << 3;
  int e0 = rowptr[n], e1 = rowptr[n + 1];
  if (e0 < 0) e0 = 0;
  if (e1 > N_EDGES) e1 = N_EDGES;
  float acc[8];
#pragma unroll
  for (int i = 0; i < 8; ++i) acc[i] = 0.f;
  spmm_gather(hs, col, e0, e1, row_sel, dim0, acc);
  float nin = norm_in[n];
  float vv[8];
  float p = 0.f;
#pragma unroll
  for (int i = 0; i < 8; ++i) {
    vv[i] = fmaxf(acc[i] * nin + b2f[dim0 + i], 0.f);  // h2[n][dim0+i]
    p += vv[i] * attnWf[dim0 + i];
  }
  // sum the 8 dim-groups: lanes sharing row_sel differ in bits 0..2
#pragma unroll
  for (int m = 1; m <= 4; m <<= 1) p += __shfl_xor(p, m, 64);
  float logit = p + attnbf[0];
  float hwv = 1.f / (1.f + __expf(-logit));
  if (lane == 0) {
    if (mode) ((unsigned short*)out_base)[N_GRAPHS * N_CLASSES + n] = f2bf(hwv);
    else      ((float*)out_base)[N_GRAPHS * N_CLASSES + n] = hwv;
  }
  if (row_sel == 0) {
    unsigned int pk[4];
#pragma unroll
    for (int i = 0; i < 4; ++i) {
      pk[i] = (unsigned int)f2bf(vv[2 * i] * hwv) |
              ((unsigned int)f2bf(vv[2 * i + 1] * hwv) << 16);
    }
    *(uint4*)(gated + ((size_t)n << 6) + dim0) = make_uint4(pk[0], pk[1], pk[2], pk[3]);
  }
}

// ---------------- pool: block per graph, contiguous range sum (no atomics) ----
__global__ __launch_bounds__(256) void pool_kernel(const unsigned short* __restrict__ gated,
                                                   const int* __restrict__ gstart,
                                                   float* __restrict__ gsum) {
  int g = (int)blockIdx.x;
  int dim = (int)threadIdx.x & 63;
  int rsel = (int)threadIdx.x >> 6;
  int r0 = gstart[g], r1 = gstart[g + 1];
  if (r0 < 0) r0 = 0;
  if (r1 > N_NODES) r1 = N_NODES;
  float acc = 0.f;
  for (int r = r0 + rsel; r < r1; r += 4)
    acc += bf2f(gated[((size_t)r << 6) + dim]);
  __shared__ float sm[256];
  sm[threadIdx.x] = acc;
  __syncthreads();
  if (threadIdx.x < 64)
    gsum[(g << 6) + dim] = sm[dim] + sm[64 + dim] + sm[128 + dim] + sm[192 + dim];
}

// ---------------- final: out[g][c] = (gsum[g]/cnt) . cls_W[:,c] + cls_b ----------
__global__ __launch_bounds__(640) void final_kernel(const float* __restrict__ gsum,
                                                    const int* __restrict__ gstart,
                                                    const float* __restrict__ clsWf,
                                                    const float* __restrict__ clsbf,
                                                    void* __restrict__ out_base,
                                                    const int* __restrict__ flag) {
  int mode = flag[0];
  int t = (int)threadIdx.x;
  if (t >= N_GRAPHS * N_CLASSES) return;
  int g = t / N_CLASSES, c = t - g * N_CLASSES;
  int cg = gstart[g + 1] - gstart[g];
  if (cg < 1) cg = 1;
  float inv = 1.f / (float)cg;
  float acc = 0.f;
#pragma unroll
  for (int d = 0; d < HID; ++d) acc += gsum[(g << 6) + d] * clsWf[d * N_CLASSES + c];
  float r = acc * inv + clsbf[c];
  if (mode) ((unsigned short*)out_base)[t] = f2bf(r);
  else      ((float*)out_base)[t] = r;
}

extern "C" void kernel_launch(void* const* d_in, const int* in_sizes, int n_in,
                              void* d_out, int out_size, void* d_ws, size_t ws_size,
                              hipStream_t stream) {
  const void* x     = d_in[0];
  const int*  ei    = (const int*)d_in[1];
  const int*  gid   = (const int*)d_in[2];
  const void* W1    = d_in[3];
  const void* b1    = d_in[4];
  const void* W2    = d_in[5];
  const void* b2    = d_in[6];
  const void* attnW = d_in[7];
  const void* attnb = d_in[8];
  const void* clsW  = d_in[9];
  const void* clsb  = d_in[10];

  if (ws_size < (size_t)WS_NEED) {
    fallback_kernel<<<(out_size + 255) / 256, 256, 0, stream>>>(
        (unsigned short*)d_out, out_size);
    return;
  }

  // ---- workspace layout (bytes). Every buffer fully written by a producer:
  // no zero-init kernel needed; safe under repeated launches.
  char* w = (char*)d_ws;
  int*   flag     = (int*)(w + 0);          //      64 (2 used, probe writes)
  int*   gstart   = (int*)(w + 64);         //     512 (gbound writes all)
  float* gsum     = (float*)(w + 576);      //   16384 (pool writes all)
  int*   bstart_d = (int*)(w + 16960);      //    1600 (392 used)
  int*   bstart_s = (int*)(w + 18560);      //    1600
  int*   blkhD    = (int*)(w + 20160);      //  306560 (196*391 ints)
  int*   blkhS    = (int*)(w + 326720);     //  306560
  int*   rowptr   = (int*)(w + 633280);     //  400064 (100001 used)
  float* norm_out = (float*)(w + 1033344);  //  400000
  float* norm_in  = (float*)(w + 1433344);  //  400000
  float* Wf1      = (float*)(w + 1833344);  //   32768
  float* Wf2      = (float*)(w + 1866112);  //   16384
  float* b1f      = (float*)(w + 1882496);  //     256
  float* b2f      = (float*)(w + 1882752);  //     256
  float* attnWf   = (float*)(w + 1883008);  //     256
  float* attnbf   = (float*)(w + 1883264);  //      64
  float* clsWf    = (float*)(w + 1883328);  //    2560
  float* clsbf    = (float*)(w + 1885888);  //      64 -> 1885952
  int*   colx     = (int*)(w + 1885952);    // 6400000 -> 8285952
  int2*  edst     = (int2*)(w + 8285952);   // 12800000 -> 21085952
  int*   esrc     = (int*)(w + 21085952);   // 6400000 -> 27485952
  // bufA aliases edst (dead after csr_kernel; gemm1 writes after).
  // bufB aliases esrc+tail (dead after csr_kernel; spmm1 writes after).
  unsigned short* bufA = (unsigned short*)(w + 8285952);   // 12800000
  unsigned short* bufB = (unsigned short*)(w + 21085952);  // 12800000 -> 33885952

  probe_kernel<<<1, 256, 0, stream>>>((const unsigned short*)x, flag);
  wcvt_kernel<<<32, 256, 0, stream>>>(W1, W2, b1, b2, attnW, attnb, clsW, clsb,
                                      Wf1, Wf2, b1f, b2f, attnWf, attnbf, clsWf,
                                      clsbf, flag);

  // P1: per-chunk bucket histograms (no global atomics) + graph boundaries
  part_count_kernel<<<P1B + GB_BLOCKS, 256, 0, stream>>>(ei, blkhD, blkhS, gid, gstart);
  // P2: bucket scan; blkh* rewritten in place to per-(block,bucket) bases
  bucket_scan_kernel<<<2, 512, 0, stream>>>(blkhD, blkhS, bstart_d, bstart_s);
  // P3: partition edges into dst-bucket (pairs) and src-bucket (src-only) arrays
  part_scatter_kernel<<<P1B, 256, 0, stream>>>(ei, blkhD, blkhS, edst, esrc);
  // P4: per-bucket counting sort -> rowptr, col, norm_in | src counts -> norm_out
  csr_kernel<<<2 * NBUCK, 256, 0, stream>>>(edst, esrc, bstart_d, bstart_s,
                                            rowptr, colx, norm_in, norm_out);

  // layer 1: hs1 = (x @ W1) * norm_out  (scale fused; norms are ready)
  gemm_kernel<IN_DIM><<<GEMM_BLOCKS, 256, 0, stream>>>(x, Wf1, norm_out, bufA, flag);
  // layer 1 aggregation: h1 = relu(Agg(hs1) * norm_in + b1)
  spmm_kernel<<<(N_NODES * 64) / 256, 256, 0, stream>>>(bufA, rowptr, colx, norm_in, b1f, bufB);

  // layer 2: hs2 = (h1 @ W2) * norm_out ; agg + relu + attention -> gated rows
  gemm_kernel<HID><<<GEMM_BLOCKS, 256, 0, stream>>>(bufB, Wf2, norm_out, bufA, flag + 1);
  spmm_attn_kernel<<<(N_NODES * 64) / 256, 256, 0, stream>>>(
      bufA, rowptr, colx, norm_in, b2f, attnWf, attnbf, d_out, bufB, flag);

  // atomic-free pooling over sorted-graph contiguous ranges
  pool_kernel<<<N_GRAPHS, 256, 0, stream>>>(bufB, gstart, gsum);
  final_kernel<<<1, 640, 0, stream>>>(gsum, gstart, clsWf, clsbf, d_out, flag);
}

// Round 3
// 322.940 us; speedup vs baseline: 1.6345x; 1.2872x over previous
//
#include <hip/hip_runtime.h>
#include <stdint.h>

// GNN: 2x GraphConv (norm='both') + attention gate + mean pooling + classifier.
// Round-10: pool_kernel was 103.7us at 2.5% occupancy (64 blocks on 256 CUs,
// latency-bound). Split pooling into 64x32=2048 slice blocks writing partials
// (aliased over dead blkh region) + tiny reduce. Build phase (atomic-free
// bucket partition from round-9) unchanged: it removed the 190us fabric-atomic
// wall (528 -> 415.7us measured).

#define N_NODES   100000
#define N_EDGES   1600000
#define N_GRAPHS  64
#define IN_DIM    128
#define HID       64
#define N_CLASSES 10

#define NBUCK     391       // ceil(100000/256) buckets of 256 nodes
#define P1B       196       // partition chunk blocks
#define EPB       8192      // edges per chunk block (196*8192 >= 1.6M)
#define GB_BLOCKS 391       // ceil(100000/256)
#define GEMM_BLOCKS 782     // ceil(100000/128)
#define POOL_SLICES 32      // blocks per graph in pooling
#define WS_NEED   33885952u

__device__ __forceinline__ float bf2f(unsigned short u) {
  unsigned int v = ((unsigned int)u) << 16;
  float f;
  __builtin_memcpy(&f, &v, 4);
  return f;
}

__device__ __forceinline__ unsigned short f2bf(float f) {
  unsigned int x;
  __builtin_memcpy(&x, &f, 4);
  unsigned int lsb = (x >> 16) & 1u;
  x += 0x7fffu + lsb;  // round-to-nearest-even
  return (unsigned short)(x >> 16);
}

__device__ __forceinline__ void unpack_bf2(unsigned int u, float& lo, float& hi) {
  unsigned int a = u << 16;
  unsigned int b = u & 0xffff0000u;
  __builtin_memcpy(&lo, &a, 4);
  __builtin_memcpy(&hi, &b, 4);
}

// mode: 1 = tensors are bf16, 0 = tensors are fp32
__device__ __forceinline__ float ldf(const void* p, int i, int mode) {
  return mode ? bf2f(((const unsigned short*)p)[i]) : ((const float*)p)[i];
}

// ---------------- dtype probe ----------------
__global__ __launch_bounds__(256) void probe_kernel(const unsigned short* __restrict__ xu,
                                                    int* __restrict__ flag) {
  int tid = (int)threadIdx.x;
  unsigned u = xu[2 * tid];
  int e = (int)((u >> 7) & 0xFF);
  int ok = (e >= 110 && e <= 132) ? 1 : 0;
  unsigned long long m = __ballot(ok);
  __shared__ int cnt[4];
  if ((tid & 63) == 0) cnt[tid >> 6] = __popcll(m);
  __syncthreads();
  if (tid == 0) {
    flag[0] = (cnt[0] + cnt[1] + cnt[2] + cnt[3] > 128) ? 1 : 0;
    flag[1] = 1;
  }
}

// ---------------- fallback (ws too small): deterministic zero output ----------
__global__ __launch_bounds__(256) void fallback_kernel(unsigned short* __restrict__ out,
                                                       int n) {
  int i = blockIdx.x * 256 + threadIdx.x;
  if (i < n) out[i] = 0;
}

// ---------------- params -> fp32 ----------------
__global__ __launch_bounds__(256) void wcvt_kernel(
    const void* __restrict__ W1, const void* __restrict__ W2,
    const void* __restrict__ b1, const void* __restrict__ b2,
    const void* __restrict__ attnW, const void* __restrict__ attnb,
    const void* __restrict__ clsW, const void* __restrict__ clsb,
    float* __restrict__ Wf1, float* __restrict__ Wf2,
    float* __restrict__ b1f, float* __restrict__ b2f,
    float* __restrict__ attnWf, float* __restrict__ attnbf,
    float* __restrict__ clsWf, float* __restrict__ clsbf,
    const int* __restrict__ flag) {
  int mode = flag[0];
  int i = blockIdx.x * 256 + threadIdx.x;
  if (i < IN_DIM * HID) Wf1[i] = ldf(W1, i, mode);
  if (i < HID * HID)    Wf2[i] = ldf(W2, i, mode);
  if (i < HID) {
    b1f[i] = ldf(b1, i, mode);
    b2f[i] = ldf(b2, i, mode);
    attnWf[i] = ldf(attnW, i, mode);
  }
  if (i == 0) attnbf[0] = ldf(attnb, 0, mode);
  if (i < HID * N_CLASSES) clsWf[i] = ldf(clsW, i, mode);
  if (i < N_CLASSES) clsbf[i] = ldf(clsb, i, mode);
}

// =============== P1: per-chunk bucket histograms (dst & src) | gbound ========
__global__ __launch_bounds__(256) void part_count_kernel(
    const int* __restrict__ ei, int* __restrict__ blkhistD,
    int* __restrict__ blkhistS,
    const int* __restrict__ gid, int* __restrict__ gstart) {
  int b = (int)blockIdx.x;
  int t = (int)threadIdx.x;
  if (b < P1B) {
    __shared__ int hD[NBUCK];
    __shared__ int hS[NBUCK];
    for (int i = t; i < NBUCK; i += 256) { hD[i] = 0; hS[i] = 0; }
    __syncthreads();
    int base_e = b * EPB;
    for (int s = 0; s < EPB / 1024; ++s) {
      int e4 = base_e + s * 1024 + t * 4;
      if (e4 < N_EDGES) {
        int4 s4 = *(const int4*)(ei + e4);
        int4 d4 = *(const int4*)(ei + N_EDGES + e4);
        int ss[4] = {s4.x, s4.y, s4.z, s4.w};
        int dd[4] = {d4.x, d4.y, d4.z, d4.w};
#pragma unroll
        for (int j = 0; j < 4; ++j) {
          if ((unsigned)ss[j] < N_NODES) atomicAdd(&hS[ss[j] >> 8], 1);
          if ((unsigned)dd[j] < N_NODES) atomicAdd(&hD[dd[j] >> 8], 1);
        }
      }
    }
    __syncthreads();
    for (int i = t; i < NBUCK; i += 256) {
      blkhistD[b * NBUCK + i] = hD[i];
      blkhistS[b * NBUCK + i] = hS[i];
    }
  } else {
    // ---- gbound part ----
    int bb = b - P1B;
    int n = bb * 256 + t;
    if (n >= N_NODES) return;
    int gc = gid[n] & (N_GRAPHS - 1);
    if (n == 0) {
      for (int g = 0; g <= gc; ++g) gstart[g] = 0;
    } else {
      int gp = gid[n - 1] & (N_GRAPHS - 1);
      for (int g = gp + 1; g <= gc; ++g) gstart[g] = n;
    }
    if (n == N_NODES - 1) {
      for (int g = gc + 1; g <= N_GRAPHS; ++g) gstart[g] = N_NODES;
    }
  }
}

// =============== P2: bucket totals scan + in-place per-block bases ===========
__global__ __launch_bounds__(512) void bucket_scan_kernel(
    int* __restrict__ blkhistD, int* __restrict__ blkhistS,
    int* __restrict__ bstart_d, int* __restrict__ bstart_s) {
  int* hist = (blockIdx.x == 0) ? blkhistD : blkhistS;
  int* bst  = (blockIdx.x == 0) ? bstart_d : bstart_s;
  int u = (int)threadIdx.x;
  int tot = 0;
  if (u < NBUCK) {
    for (int blk = 0; blk < P1B; ++blk) tot += hist[blk * NBUCK + u];
  }
  __shared__ int smA[512];
  __shared__ int smB[512];
  smA[u] = tot;
  __syncthreads();
  int* a = smA;
  int* bq = smB;
  for (int off = 1; off < 512; off <<= 1) {
    int v = a[u];
    if (u >= off) v += a[u - off];
    bq[u] = v;
    __syncthreads();
    int* tmp = a; a = bq; bq = tmp;
  }
  int excl = a[u] - tot;
  if (u <= NBUCK) bst[u] = excl;  // u==NBUCK: tot==0 -> excl == total
  if (u < NBUCK) {
    int off2 = excl;
    for (int blk = 0; blk < P1B; ++blk) {
      int h = hist[blk * NBUCK + u];
      hist[blk * NBUCK + u] = off2;
      off2 += h;
    }
  }
}

// =============== P3: scatter edges into bucket-partitioned arrays ============
__global__ __launch_bounds__(256) void part_scatter_kernel(
    const int* __restrict__ ei, const int* __restrict__ blkbaseD,
    const int* __restrict__ blkbaseS,
    int2* __restrict__ edst, int* __restrict__ esrc) {
  __shared__ int cD[NBUCK];
  __shared__ int cS[NBUCK];
  int b = (int)blockIdx.x;
  int t = (int)threadIdx.x;
  for (int i = t; i < NBUCK; i += 256) {
    cD[i] = blkbaseD[b * NBUCK + i];
    cS[i] = blkbaseS[b * NBUCK + i];
  }
  __syncthreads();
  int base_e = b * EPB;
  for (int s = 0; s < EPB / 1024; ++s) {
    int e4 = base_e + s * 1024 + t * 4;
    if (e4 < N_EDGES) {
      int4 s4 = *(const int4*)(ei + e4);
      int4 d4 = *(const int4*)(ei + N_EDGES + e4);
      int ss[4] = {s4.x, s4.y, s4.z, s4.w};
      int dd[4] = {d4.x, d4.y, d4.z, d4.w};
#pragma unroll
      for (int j = 0; j < 4; ++j) {
        if ((unsigned)ss[j] < N_NODES) {
          int slot = atomicAdd(&cS[ss[j] >> 8], 1);
          esrc[slot] = ss[j];
        }
        if ((unsigned)dd[j] < N_NODES) {
          int slot = atomicAdd(&cD[dd[j] >> 8], 1);
          edst[slot] = make_int2(ss[j], dd[j]);
        }
      }
    }
  }
}

// =============== P4: per-bucket counting sort -> rowptr/col/norms ============
__global__ __launch_bounds__(256) void csr_kernel(
    const int2* __restrict__ edst, const int* __restrict__ esrc,
    const int* __restrict__ bstart_d, const int* __restrict__ bstart_s,
    int* __restrict__ rowptr, int* __restrict__ colx,
    float* __restrict__ norm_in, float* __restrict__ norm_out) {
  __shared__ int lc[256];
  __shared__ int smA[256];
  __shared__ int smB[256];
  int b = (int)blockIdx.x;
  int t = (int)threadIdx.x;
  if (b < NBUCK) {
    int node0 = b << 8;
    int base = bstart_d[b];
    int end  = bstart_d[b + 1];
    lc[t] = 0;
    __syncthreads();
    for (int i = base + t; i < end; i += 256) {
      int2 p = edst[i];
      atomicAdd(&lc[p.y - node0], 1);
    }
    __syncthreads();
    int my = lc[t];
    smA[t] = my;
    __syncthreads();
    int* a = smA;
    int* bq = smB;
    for (int off = 1; off < 256; off <<= 1) {
      int v = a[t];
      if (t >= off) v += a[t - off];
      bq[t] = v;
      __syncthreads();
      int* tmp = a; a = bq; bq = tmp;
    }
    int excl = a[t] - my;
    int n = node0 + t;
    if (n <= N_NODES) rowptr[n] = base + excl;
    if (n < N_NODES) {
      int c = my < 1 ? 1 : my;
      norm_in[n] = rsqrtf((float)c);
    }
    __syncthreads();
    lc[t] = base + excl;  // per-node cursor
    __syncthreads();
    for (int i = base + t; i < end; i += 256) {
      int2 p = edst[i];
      int slot = atomicAdd(&lc[p.y - node0], 1);
      colx[slot] = p.x;
    }
  } else {
    int bb = b - NBUCK;
    int node0 = bb << 8;
    int base = bstart_s[bb];
    int end  = bstart_s[bb + 1];
    lc[t] = 0;
    __syncthreads();
    for (int i = base + t; i < end; i += 256) {
      atomicAdd(&lc[esrc[i] - node0], 1);
    }
    __syncthreads();
    int n = node0 + t;
    if (n < N_NODES) {
      int c = lc[t] < 1 ? 1 : lc[t];
      norm_out[n] = rsqrtf((float)c);
    }
  }
}

// ---------------- GEMM (with norm scaling): out = (A . Wf) * norm_out --------
template <int K>
__global__ __launch_bounds__(256) void gemm_kernel(const void* __restrict__ A,
                                                   const float* __restrict__ Wf,
                                                   const float* __restrict__ norm_out,
                                                   unsigned short* __restrict__ out,
                                                   const int* __restrict__ flag) {
  int mode = flag[0];
  int n = blockIdx.x * 128 + ((int)threadIdx.x & 127);
  int d0 = __builtin_amdgcn_readfirstlane((int)((threadIdx.x >> 7) << 5));
  if (n >= N_NODES) return;
  float acc[32];
#pragma unroll
  for (int i = 0; i < 32; ++i) acc[i] = 0.f;
  if (mode) {
    const unsigned short* xr = (const unsigned short*)A + (size_t)n * K;
    for (int k0 = 0; k0 < K; k0 += 8) {
      uint4 xv = *(const uint4*)(xr + k0);
      float xf[8];
      unpack_bf2(xv.x, xf[0], xf[1]);
      unpack_bf2(xv.y, xf[2], xf[3]);
      unpack_bf2(xv.z, xf[4], xf[5]);
      unpack_bf2(xv.w, xf[6], xf[7]);
#pragma unroll
      for (int j = 0; j < 8; ++j) {
        const float* wrow = Wf + (k0 + j) * HID + d0;
#pragma unroll
        for (int d = 0; d < 32; ++d) acc[d] += xf[j] * wrow[d];
      }
    }
  } else {
    const float* xr = (const float*)A + (size_t)n * K;
    for (int k0 = 0; k0 < K; k0 += 8) {
      float4 a0 = *(const float4*)(xr + k0);
      float4 a1 = *(const float4*)(xr + k0 + 4);
      float xf[8] = {a0.x, a0.y, a0.z, a0.w, a1.x, a1.y, a1.z, a1.w};
#pragma unroll
      for (int j = 0; j < 8; ++j) {
        const float* wrow = Wf + (k0 + j) * HID + d0;
#pragma unroll
        for (int d = 0; d < 32; ++d) acc[d] += xf[j] * wrow[d];
      }
    }
  }
  float s = norm_out[n];
  unsigned short* orow = out + (size_t)n * HID + d0;
#pragma unroll
  for (int d = 0; d < 32; ++d) orow[d] = f2bf(acc[d] * s);
}

// ---------------- SpMM gather core: 32 edges in flight per iteration ----------
__device__ __forceinline__ void spmm_gather(const unsigned short* __restrict__ hs,
                                            const int* __restrict__ col,
                                            int e0, int e1, int row_sel, int dim0,
                                            float acc[8]) {
  for (int e = e0; e < e1; e += 32) {
    uint4 v[4];
#pragma unroll
    for (int j = 0; j < 4; ++j) {
      v[j] = make_uint4(0u, 0u, 0u, 0u);
      int ee = e + (j << 3) + row_sel;
      if (ee < e1) {
        unsigned s = (unsigned)col[ee];
        if (s < N_NODES) v[j] = *(const uint4*)(hs + ((size_t)s << 6) + dim0);
      }
    }
#pragma unroll
    for (int j = 0; j < 4; ++j) {
      float lo, hi;
      unpack_bf2(v[j].x, lo, hi); acc[0] += lo; acc[1] += hi;
      unpack_bf2(v[j].y, lo, hi); acc[2] += lo; acc[3] += hi;
      unpack_bf2(v[j].z, lo, hi); acc[4] += lo; acc[5] += hi;
      unpack_bf2(v[j].w, lo, hi); acc[6] += lo; acc[7] += hi;
    }
  }
  // fold the 8 edge-groups: lanes sharing (lane&7) differ in bits 3..5
#pragma unroll
  for (int m = 8; m <= 32; m <<= 1) {
#pragma unroll
    for (int i = 0; i < 8; ++i) acc[i] += __shfl_xor(acc[i], m, 64);
  }
}

// ---------------- SpMM layer-1: wave per node ----------------
__global__ __launch_bounds__(256) void spmm_kernel(const unsigned short* __restrict__ hs,
                                                   const int* __restrict__ rowptr,
                                                   const int* __restrict__ col,
                                                   const float* __restrict__ norm_in,
                                                   const float* __restrict__ b1f,
                                                   unsigned short* __restrict__ out) {
  int n = (int)((blockIdx.x * 256 + threadIdx.x) >> 6);
  int lane = (int)threadIdx.x & 63;
  if (n >= N_NODES) return;
  int row_sel = lane >> 3;
  int dim0 = (lane & 7) << 3;
  int e0 = rowptr[n], e1 = rowptr[n + 1];
  if (e0 < 0) e0 = 0;
  if (e1 > N_EDGES) e1 = N_EDGES;
  float acc[8];
#pragma unroll
  for (int i = 0; i < 8; ++i) acc[i] = 0.f;
  spmm_gather(hs, col, e0, e1, row_sel, dim0, acc);
  if (row_sel == 0) {
    float nin = norm_in[n];
    unsigned int pk[4];
#pragma unroll
    for (int i = 0; i < 4; ++i) {
      float vlo = fmaxf(acc[2 * i] * nin + b1f[dim0 + 2 * i], 0.f);
      float vhi = fmaxf(acc[2 * i + 1] * nin + b1f[dim0 + 2 * i + 1], 0.f);
      pk[i] = (unsigned int)f2bf(vlo) | ((unsigned int)f2bf(vhi) << 16);
    }
    *(uint4*)(out + ((size_t)n << 6) + dim0) = make_uint4(pk[0], pk[1], pk[2], pk[3]);
  }
}

// ------- SpMM layer-2 fused with attention gate; writes gated bf16 rows -------
__global__ __launch_bounds__(256) void spmm_attn_kernel(
    const unsigned short* __restrict__ hs,
    const int* __restrict__ rowptr, const int* __restrict__ col,
    const float* __restrict__ norm_in, const float* __restrict__ b2f,
    const float* __restrict__ attnWf, const float* __restrict__ attnbf,
    void* __restrict__ out_base, unsigned short* __restrict__ gated,
    const int* __restrict__ flag) {
  int mode = flag[0];
  int n = (int)((blockIdx.x * 256 + threadIdx.x) >> 6);
  int lane = (int)threadIdx.x & 63;
  if (n >= N_NODES) return;
  int row_sel = lane >> 3;
  int dim0 = (lane & 7) << 3;
  int e0 = rowptr[n], e1 = rowptr[n + 1];
  if (e0 < 0) e0 = 0;
  if (e1 > N_EDGES) e1 = N_EDGES;
  float acc[8];
#pragma unroll
  for (int i = 0; i < 8; ++i) acc[i] = 0.f;
  spmm_gather(hs, col, e0, e1, row_sel, dim0, acc);
  float nin = norm_in[n];
  float vv[8];
  float p = 0.f;
#pragma unroll
  for (int i = 0; i < 8; ++i) {
    vv[i] = fmaxf(acc[i] * nin + b2f[dim0 + i], 0.f);  // h2[n][dim0+i]
    p += vv[i] * attnWf[dim0 + i];
  }
  // sum the 8 dim-groups: lanes sharing row_sel differ in bits 0..2
#pragma unroll
  for (int m = 1; m <= 4; m <<= 1) p += __shfl_xor(p, m, 64);
  float logit = p + attnbf[0];
  float hwv = 1.f / (1.f + __expf(-logit));
  if (lane == 0) {
    if (mode) ((unsigned short*)out_base)[N_GRAPHS * N_CLASSES + n] = f2bf(hwv);
    else      ((float*)out_base)[N_GRAPHS * N_CLASSES + n] = hwv;
  }
  if (row_sel == 0) {
    unsigned int pk[4];
#pragma unroll
    for (int i = 0; i < 4; ++i) {
      pk[i] = (unsigned int)f2bf(vv[2 * i] * hwv) |
              ((unsigned int)f2bf(vv[2 * i + 1] * hwv) << 16);
    }
    *(uint4*)(gated + ((size_t)n << 6) + dim0) = make_uint4(pk[0], pk[1], pk[2], pk[3]);
  }
}

// -------- pool: 64 graphs x 32 slices, partial sums (occupancy fix) ----------
__global__ __launch_bounds__(256) void pool_kernel(const unsigned short* __restrict__ gated,
                                                   const int* __restrict__ gstart,
                                                   float* __restrict__ gpart) {
  int g = (int)blockIdx.x >> 5;         // graph
  int s = (int)blockIdx.x & 31;         // slice
  int dim = (int)threadIdx.x & 63;
  int rsel = (int)threadIdx.x >> 6;
  int r0 = gstart[g], r1 = gstart[g + 1];
  if (r0 < 0) r0 = 0;
  if (r1 > N_NODES) r1 = N_NODES;
  int len = r1 - r0;
  if (len < 0) len = 0;
  int a = r0 + (int)(((long long)len * s) >> 5);
  int bnd = r0 + (int)(((long long)len * (s + 1)) >> 5);
  float acc = 0.f;
  for (int r = a + rsel; r < bnd; r += 4)
    acc += bf2f(gated[((size_t)r << 6) + dim]);
  __shared__ float sm[256];
  sm[threadIdx.x] = acc;
  __syncthreads();
  if (threadIdx.x < 64)
    gpart[((size_t)blockIdx.x << 6) + dim] =
        sm[dim] + sm[64 + dim] + sm[128 + dim] + sm[192 + dim];
}

// -------- pool reduce: gsum[g][dim] = sum over 32 slice partials -------------
__global__ __launch_bounds__(64) void pool_reduce_kernel(const float* __restrict__ gpart,
                                                         float* __restrict__ gsum) {
  int g = (int)blockIdx.x;
  int dim = (int)threadIdx.x;
  float acc = 0.f;
#pragma unroll
  for (int s = 0; s < POOL_SLICES; ++s)
    acc += gpart[(((size_t)g << 5) + s << 6) + dim];
  gsum[((size_t)g << 6) + dim] = acc;
}

// ---------------- final: out[g][c] = (gsum[g]/cnt) . cls_W[:,c] + cls_b ----------
__global__ __launch_bounds__(640) void final_kernel(const float* __restrict__ gsum,
                                                    const int* __restrict__ gstart,
                                                    const float* __restrict__ clsWf,
                                                    const float* __restrict__ clsbf,
                                                    void* __restrict__ out_base,
                                                    const int* __restrict__ flag) {
  int mode = flag[0];
  int t = (int)threadIdx.x;
  if (t >= N_GRAPHS * N_CLASSES) return;
  int g = t / N_CLASSES, c = t - g * N_CLASSES;
  int cg = gstart[g + 1] - gstart[g];
  if (cg < 1) cg = 1;
  float inv = 1.f / (float)cg;
  float acc = 0.f;
#pragma unroll
  for (int d = 0; d < HID; ++d) acc += gsum[(g << 6) + d] * clsWf[d * N_CLASSES + c];
  float r = acc * inv + clsbf[c];
  if (mode) ((unsigned short*)out_base)[t] = f2bf(r);
  else      ((float*)out_base)[t] = r;
}

extern "C" void kernel_launch(void* const* d_in, const int* in_sizes, int n_in,
                              void* d_out, int out_size, void* d_ws, size_t ws_size,
                              hipStream_t stream) {
  const void* x     = d_in[0];
  const int*  ei    = (const int*)d_in[1];
  const int*  gid   = (const int*)d_in[2];
  const void* W1    = d_in[3];
  const void* b1    = d_in[4];
  const void* W2    = d_in[5];
  const void* b2    = d_in[6];
  const void* attnW = d_in[7];
  const void* attnb = d_in[8];
  const void* clsW  = d_in[9];
  const void* clsb  = d_in[10];

  if (ws_size < (size_t)WS_NEED) {
    fallback_kernel<<<(out_size + 255) / 256, 256, 0, stream>>>(
        (unsigned short*)d_out, out_size);
    return;
  }

  // ---- workspace layout (bytes). Every buffer fully written by a producer:
  // no zero-init kernel needed; safe under repeated launches.
  char* w = (char*)d_ws;
  int*   flag     = (int*)(w + 0);          //      64 (2 used, probe writes)
  int*   gstart   = (int*)(w + 64);         //     512 (gbound writes all)
  float* gsum     = (float*)(w + 576);      //   16384 (pool_reduce writes all)
  int*   bstart_d = (int*)(w + 16960);      //    1600 (392 used)
  int*   bstart_s = (int*)(w + 18560);      //    1600
  int*   blkhD    = (int*)(w + 20160);      //  306560 (196*391 ints)
  int*   blkhS    = (int*)(w + 326720);     //  306560
  int*   rowptr   = (int*)(w + 633280);     //  400064 (100001 used)
  float* norm_out = (float*)(w + 1033344);  //  400000
  float* norm_in  = (float*)(w + 1433344);  //  400000
  float* Wf1      = (float*)(w + 1833344);  //   32768
  float* Wf2      = (float*)(w + 1866112);  //   16384
  float* b1f      = (float*)(w + 1882496);  //     256
  float* b2f      = (float*)(w + 1882752);  //     256
  float* attnWf   = (float*)(w + 1883008);  //     256
  float* attnbf   = (float*)(w + 1883264);  //      64
  float* clsWf    = (float*)(w + 1883328);  //    2560
  float* clsbf    = (float*)(w + 1885888);  //      64 -> 1885952
  int*   colx     = (int*)(w + 1885952);    // 6400000 -> 8285952
  int2*  edst     = (int2*)(w + 8285952);   // 12800000 -> 21085952
  int*   esrc     = (int*)(w + 21085952);   // 6400000 -> 27485952
  // bufA aliases edst (dead after csr_kernel; gemm1 writes after).
  // bufB aliases esrc+tail (dead after csr_kernel; spmm1 writes after).
  unsigned short* bufA = (unsigned short*)(w + 8285952);   // 12800000
  unsigned short* bufB = (unsigned short*)(w + 21085952);  // 12800000 -> 33885952
  // gpart aliases blkhD/S (dead after part_scatter consumes the bases):
  // 64 graphs * 32 slices * 64 dims * 4B = 524288 <= 613120 available.
  float* gpart    = (float*)(w + 20160);

  probe_kernel<<<1, 256, 0, stream>>>((const unsigned short*)x, flag);
  wcvt_kernel<<<32, 256, 0, stream>>>(W1, W2, b1, b2, attnW, attnb, clsW, clsb,
                                      Wf1, Wf2, b1f, b2f, attnWf, attnbf, clsWf,
                                      clsbf, flag);

  // P1: per-chunk bucket histograms (no global atomics) + graph boundaries
  part_count_kernel<<<P1B + GB_BLOCKS, 256, 0, stream>>>(ei, blkhD, blkhS, gid, gstart);
  // P2: bucket scan; blkh* rewritten in place to per-(block,bucket) bases
  bucket_scan_kernel<<<2, 512, 0, stream>>>(blkhD, blkhS, bstart_d, bstart_s);
  // P3: partition edges into dst-bucket (pairs) and src-bucket (src-only) arrays
  part_scatter_kernel<<<P1B, 256, 0, stream>>>(ei, blkhD, blkhS, edst, esrc);
  // P4: per-bucket counting sort -> rowptr, col, norm_in | src counts -> norm_out
  csr_kernel<<<2 * NBUCK, 256, 0, stream>>>(edst, esrc, bstart_d, bstart_s,
                                            rowptr, colx, norm_in, norm_out);

  // layer 1: hs1 = (x @ W1) * norm_out  (scale fused; norms are ready)
  gemm_kernel<IN_DIM><<<GEMM_BLOCKS, 256, 0, stream>>>(x, Wf1, norm_out, bufA, flag);
  // layer 1 aggregation: h1 = relu(Agg(hs1) * norm_in + b1)
  spmm_kernel<<<(N_NODES * 64) / 256, 256, 0, stream>>>(bufA, rowptr, colx, norm_in, b1f, bufB);

  // layer 2: hs2 = (h1 @ W2) * norm_out ; agg + relu + attention -> gated rows
  gemm_kernel<HID><<<GEMM_BLOCKS, 256, 0, stream>>>(bufB, Wf2, norm_out, bufA, flag + 1);
  spmm_attn_kernel<<<(N_NODES * 64) / 256, 256, 0, stream>>>(
      bufA, rowptr, colx, norm_in, b2f, attnWf, attnbf, d_out, bufB, flag);

  // pooling: 2048 slice blocks -> partials (occupancy fix), then tiny reduce
  pool_kernel<<<N_GRAPHS * POOL_SLICES, 256, 0, stream>>>(bufB, gstart, gpart);
  pool_reduce_kernel<<<N_GRAPHS, 64, 0, stream>>>(gpart, gsum);
  final_kernel<<<1, 640, 0, stream>>>(gsum, gstart, clsWf, clsbf, d_out, flag);
}

// Round 4
// 297.758 us; speedup vs baseline: 1.7727x; 1.0846x over previous
//
#include <hip/hip_runtime.h>
#include <stdint.h>

// GNN: 2x GraphConv (norm='both') + attention gate + mean pooling + classifier.
// Round-11: spmm pair was ~100us at VALUBusy 80% / HBM 25% (VALU-issue bound).
// Old scheme (wave per node, 8 row_sel groups) paid 48 insts/node of shuffle
// fold + half-empty 32-edge strides at mean deg 16. New scheme: 8 lanes per
// node, each lane owns 8 dims and serially accumulates all edges (4-deep
// unrolled gathers) -> no fold, no empty slots, ~2.4x fewer wave-insts.
// Build phase (atomic-free bucket partition) and split pooling unchanged
// (528 -> 415.7 -> 322.9us measured so far).

#define N_NODES   100000
#define N_EDGES   1600000
#define N_GRAPHS  64
#define IN_DIM    128
#define HID       64
#define N_CLASSES 10

#define NBUCK     391       // ceil(100000/256) buckets of 256 nodes
#define P1B       196       // partition chunk blocks
#define EPB       8192      // edges per chunk block (196*8192 >= 1.6M)
#define GB_BLOCKS 391       // ceil(100000/256)
#define GEMM_BLOCKS 782     // ceil(100000/128)
#define SPMM_BLOCKS 3125    // 100000 / 32 nodes per block
#define POOL_SLICES 32      // blocks per graph in pooling
#define WS_NEED   33885952u

__device__ __forceinline__ float bf2f(unsigned short u) {
  unsigned int v = ((unsigned int)u) << 16;
  float f;
  __builtin_memcpy(&f, &v, 4);
  return f;
}

__device__ __forceinline__ unsigned short f2bf(float f) {
  unsigned int x;
  __builtin_memcpy(&x, &f, 4);
  unsigned int lsb = (x >> 16) & 1u;
  x += 0x7fffu + lsb;  // round-to-nearest-even
  return (unsigned short)(x >> 16);
}

__device__ __forceinline__ void unpack_bf2(unsigned int u, float& lo, float& hi) {
  unsigned int a = u << 16;
  unsigned int b = u & 0xffff0000u;
  __builtin_memcpy(&lo, &a, 4);
  __builtin_memcpy(&hi, &b, 4);
}

// mode: 1 = tensors are bf16, 0 = tensors are fp32
__device__ __forceinline__ float ldf(const void* p, int i, int mode) {
  return mode ? bf2f(((const unsigned short*)p)[i]) : ((const float*)p)[i];
}

// ---------------- dtype probe ----------------
__global__ __launch_bounds__(256) void probe_kernel(const unsigned short* __restrict__ xu,
                                                    int* __restrict__ flag) {
  int tid = (int)threadIdx.x;
  unsigned u = xu[2 * tid];
  int e = (int)((u >> 7) & 0xFF);
  int ok = (e >= 110 && e <= 132) ? 1 : 0;
  unsigned long long m = __ballot(ok);
  __shared__ int cnt[4];
  if ((tid & 63) == 0) cnt[tid >> 6] = __popcll(m);
  __syncthreads();
  if (tid == 0) {
    flag[0] = (cnt[0] + cnt[1] + cnt[2] + cnt[3] > 128) ? 1 : 0;
    flag[1] = 1;
  }
}

// ---------------- fallback (ws too small): deterministic zero output ----------
__global__ __launch_bounds__(256) void fallback_kernel(unsigned short* __restrict__ out,
                                                       int n) {
  int i = blockIdx.x * 256 + threadIdx.x;
  if (i < n) out[i] = 0;
}

// ---------------- params -> fp32 ----------------
__global__ __launch_bounds__(256) void wcvt_kernel(
    const void* __restrict__ W1, const void* __restrict__ W2,
    const void* __restrict__ b1, const void* __restrict__ b2,
    const void* __restrict__ attnW, const void* __restrict__ attnb,
    const void* __restrict__ clsW, const void* __restrict__ clsb,
    float* __restrict__ Wf1, float* __restrict__ Wf2,
    float* __restrict__ b1f, float* __restrict__ b2f,
    float* __restrict__ attnWf, float* __restrict__ attnbf,
    float* __restrict__ clsWf, float* __restrict__ clsbf,
    const int* __restrict__ flag) {
  int mode = flag[0];
  int i = blockIdx.x * 256 + threadIdx.x;
  if (i < IN_DIM * HID) Wf1[i] = ldf(W1, i, mode);
  if (i < HID * HID)    Wf2[i] = ldf(W2, i, mode);
  if (i < HID) {
    b1f[i] = ldf(b1, i, mode);
    b2f[i] = ldf(b2, i, mode);
    attnWf[i] = ldf(attnW, i, mode);
  }
  if (i == 0) attnbf[0] = ldf(attnb, 0, mode);
  if (i < HID * N_CLASSES) clsWf[i] = ldf(clsW, i, mode);
  if (i < N_CLASSES) clsbf[i] = ldf(clsb, i, mode);
}

// =============== P1: per-chunk bucket histograms (dst & src) | gbound ========
__global__ __launch_bounds__(256) void part_count_kernel(
    const int* __restrict__ ei, int* __restrict__ blkhistD,
    int* __restrict__ blkhistS,
    const int* __restrict__ gid, int* __restrict__ gstart) {
  int b = (int)blockIdx.x;
  int t = (int)threadIdx.x;
  if (b < P1B) {
    __shared__ int hD[NBUCK];
    __shared__ int hS[NBUCK];
    for (int i = t; i < NBUCK; i += 256) { hD[i] = 0; hS[i] = 0; }
    __syncthreads();
    int base_e = b * EPB;
    for (int s = 0; s < EPB / 1024; ++s) {
      int e4 = base_e + s * 1024 + t * 4;
      if (e4 < N_EDGES) {
        int4 s4 = *(const int4*)(ei + e4);
        int4 d4 = *(const int4*)(ei + N_EDGES + e4);
        int ss[4] = {s4.x, s4.y, s4.z, s4.w};
        int dd[4] = {d4.x, d4.y, d4.z, d4.w};
#pragma unroll
        for (int j = 0; j < 4; ++j) {
          if ((unsigned)ss[j] < N_NODES) atomicAdd(&hS[ss[j] >> 8], 1);
          if ((unsigned)dd[j] < N_NODES) atomicAdd(&hD[dd[j] >> 8], 1);
        }
      }
    }
    __syncthreads();
    for (int i = t; i < NBUCK; i += 256) {
      blkhistD[b * NBUCK + i] = hD[i];
      blkhistS[b * NBUCK + i] = hS[i];
    }
  } else {
    // ---- gbound part ----
    int bb = b - P1B;
    int n = bb * 256 + t;
    if (n >= N_NODES) return;
    int gc = gid[n] & (N_GRAPHS - 1);
    if (n == 0) {
      for (int g = 0; g <= gc; ++g) gstart[g] = 0;
    } else {
      int gp = gid[n - 1] & (N_GRAPHS - 1);
      for (int g = gp + 1; g <= gc; ++g) gstart[g] = n;
    }
    if (n == N_NODES - 1) {
      for (int g = gc + 1; g <= N_GRAPHS; ++g) gstart[g] = N_NODES;
    }
  }
}

// =============== P2: bucket totals scan + in-place per-block bases ===========
__global__ __launch_bounds__(512) void bucket_scan_kernel(
    int* __restrict__ blkhistD, int* __restrict__ blkhistS,
    int* __restrict__ bstart_d, int* __restrict__ bstart_s) {
  int* hist = (blockIdx.x == 0) ? blkhistD : blkhistS;
  int* bst  = (blockIdx.x == 0) ? bstart_d : bstart_s;
  int u = (int)threadIdx.x;
  int tot = 0;
  if (u < NBUCK) {
    for (int blk = 0; blk < P1B; ++blk) tot += hist[blk * NBUCK + u];
  }
  __shared__ int smA[512];
  __shared__ int smB[512];
  smA[u] = tot;
  __syncthreads();
  int* a = smA;
  int* bq = smB;
  for (int off = 1; off < 512; off <<= 1) {
    int v = a[u];
    if (u >= off) v += a[u - off];
    bq[u] = v;
    __syncthreads();
    int* tmp = a; a = bq; bq = tmp;
  }
  int excl = a[u] - tot;
  if (u <= NBUCK) bst[u] = excl;  // u==NBUCK: tot==0 -> excl == total
  if (u < NBUCK) {
    int off2 = excl;
    for (int blk = 0; blk < P1B; ++blk) {
      int h = hist[blk * NBUCK + u];
      hist[blk * NBUCK + u] = off2;
      off2 += h;
    }
  }
}

// =============== P3: scatter edges into bucket-partitioned arrays ============
__global__ __launch_bounds__(256) void part_scatter_kernel(
    const int* __restrict__ ei, const int* __restrict__ blkbaseD,
    const int* __restrict__ blkbaseS,
    int2* __restrict__ edst, int* __restrict__ esrc) {
  __shared__ int cD[NBUCK];
  __shared__ int cS[NBUCK];
  int b = (int)blockIdx.x;
  int t = (int)threadIdx.x;
  for (int i = t; i < NBUCK; i += 256) {
    cD[i] = blkbaseD[b * NBUCK + i];
    cS[i] = blkbaseS[b * NBUCK + i];
  }
  __syncthreads();
  int base_e = b * EPB;
  for (int s = 0; s < EPB / 1024; ++s) {
    int e4 = base_e + s * 1024 + t * 4;
    if (e4 < N_EDGES) {
      int4 s4 = *(const int4*)(ei + e4);
      int4 d4 = *(const int4*)(ei + N_EDGES + e4);
      int ss[4] = {s4.x, s4.y, s4.z, s4.w};
      int dd[4] = {d4.x, d4.y, d4.z, d4.w};
#pragma unroll
      for (int j = 0; j < 4; ++j) {
        if ((unsigned)ss[j] < N_NODES) {
          int slot = atomicAdd(&cS[ss[j] >> 8], 1);
          esrc[slot] = ss[j];
        }
        if ((unsigned)dd[j] < N_NODES) {
          int slot = atomicAdd(&cD[dd[j] >> 8], 1);
          edst[slot] = make_int2(ss[j], dd[j]);
        }
      }
    }
  }
}

// =============== P4: per-bucket counting sort -> rowptr/col/norms ============
__global__ __launch_bounds__(256) void csr_kernel(
    const int2* __restrict__ edst, const int* __restrict__ esrc,
    const int* __restrict__ bstart_d, const int* __restrict__ bstart_s,
    int* __restrict__ rowptr, int* __restrict__ colx,
    float* __restrict__ norm_in, float* __restrict__ norm_out) {
  __shared__ int lc[256];
  __shared__ int smA[256];
  __shared__ int smB[256];
  int b = (int)blockIdx.x;
  int t = (int)threadIdx.x;
  if (b < NBUCK) {
    int node0 = b << 8;
    int base = bstart_d[b];
    int end  = bstart_d[b + 1];
    lc[t] = 0;
    __syncthreads();
    for (int i = base + t; i < end; i += 256) {
      int2 p = edst[i];
      atomicAdd(&lc[p.y - node0], 1);
    }
    __syncthreads();
    int my = lc[t];
    smA[t] = my;
    __syncthreads();
    int* a = smA;
    int* bq = smB;
    for (int off = 1; off < 256; off <<= 1) {
      int v = a[t];
      if (t >= off) v += a[t - off];
      bq[t] = v;
      __syncthreads();
      int* tmp = a; a = bq; bq = tmp;
    }
    int excl = a[t] - my;
    int n = node0 + t;
    if (n <= N_NODES) rowptr[n] = base + excl;
    if (n < N_NODES) {
      int c = my < 1 ? 1 : my;
      norm_in[n] = rsqrtf((float)c);
    }
    __syncthreads();
    lc[t] = base + excl;  // per-node cursor
    __syncthreads();
    for (int i = base + t; i < end; i += 256) {
      int2 p = edst[i];
      int slot = atomicAdd(&lc[p.y - node0], 1);
      colx[slot] = p.x;
    }
  } else {
    int bb = b - NBUCK;
    int node0 = bb << 8;
    int base = bstart_s[bb];
    int end  = bstart_s[bb + 1];
    lc[t] = 0;
    __syncthreads();
    for (int i = base + t; i < end; i += 256) {
      atomicAdd(&lc[esrc[i] - node0], 1);
    }
    __syncthreads();
    int n = node0 + t;
    if (n < N_NODES) {
      int c = lc[t] < 1 ? 1 : lc[t];
      norm_out[n] = rsqrtf((float)c);
    }
  }
}

// ---------------- GEMM (with norm scaling): out = (A . Wf) * norm_out --------
template <int K>
__global__ __launch_bounds__(256) void gemm_kernel(const void* __restrict__ A,
                                                   const float* __restrict__ Wf,
                                                   const float* __restrict__ norm_out,
                                                   unsigned short* __restrict__ out,
                                                   const int* __restrict__ flag) {
  int mode = flag[0];
  int n = blockIdx.x * 128 + ((int)threadIdx.x & 127);
  int d0 = __builtin_amdgcn_readfirstlane((int)((threadIdx.x >> 7) << 5));
  if (n >= N_NODES) return;
  float acc[32];
#pragma unroll
  for (int i = 0; i < 32; ++i) acc[i] = 0.f;
  if (mode) {
    const unsigned short* xr = (const unsigned short*)A + (size_t)n * K;
    for (int k0 = 0; k0 < K; k0 += 8) {
      uint4 xv = *(const uint4*)(xr + k0);
      float xf[8];
      unpack_bf2(xv.x, xf[0], xf[1]);
      unpack_bf2(xv.y, xf[2], xf[3]);
      unpack_bf2(xv.z, xf[4], xf[5]);
      unpack_bf2(xv.w, xf[6], xf[7]);
#pragma unroll
      for (int j = 0; j < 8; ++j) {
        const float* wrow = Wf + (k0 + j) * HID + d0;
#pragma unroll
        for (int d = 0; d < 32; ++d) acc[d] += xf[j] * wrow[d];
      }
    }
  } else {
    const float* xr = (const float*)A + (size_t)n * K;
    for (int k0 = 0; k0 < K; k0 += 8) {
      float4 a0 = *(const float4*)(xr + k0);
      float4 a1 = *(const float4*)(xr + k0 + 4);
      float xf[8] = {a0.x, a0.y, a0.z, a0.w, a1.x, a1.y, a1.z, a1.w};
#pragma unroll
      for (int j = 0; j < 8; ++j) {
        const float* wrow = Wf + (k0 + j) * HID + d0;
#pragma unroll
        for (int d = 0; d < 32; ++d) acc[d] += xf[j] * wrow[d];
      }
    }
  }
  float s = norm_out[n];
  unsigned short* orow = out + (size_t)n * HID + d0;
#pragma unroll
  for (int d = 0; d < 32; ++d) orow[d] = f2bf(acc[d] * s);
}

// ---------------- SpMM core: 8 lanes per node, serial edges, no fold ---------
__device__ __forceinline__ void accum8(uint4 v, float acc[8]) {
  float lo, hi;
  unpack_bf2(v.x, lo, hi); acc[0] += lo; acc[1] += hi;
  unpack_bf2(v.y, lo, hi); acc[2] += lo; acc[3] += hi;
  unpack_bf2(v.z, lo, hi); acc[4] += lo; acc[5] += hi;
  unpack_bf2(v.w, lo, hi); acc[6] += lo; acc[7] += hi;
}

__device__ __forceinline__ void spmm_gather8(const unsigned short* __restrict__ hs,
                                             const int* __restrict__ col,
                                             int e0, int e1, int dim0,
                                             float acc[8]) {
  int e = e0;
  for (; e + 4 <= e1; e += 4) {
    unsigned c0 = (unsigned)col[e];
    unsigned c1 = (unsigned)col[e + 1];
    unsigned c2 = (unsigned)col[e + 2];
    unsigned c3 = (unsigned)col[e + 3];
    uint4 v0 = make_uint4(0u, 0u, 0u, 0u);
    uint4 v1 = v0, v2 = v0, v3 = v0;
    if (c0 < N_NODES) v0 = *(const uint4*)(hs + ((size_t)c0 << 6) + dim0);
    if (c1 < N_NODES) v1 = *(const uint4*)(hs + ((size_t)c1 << 6) + dim0);
    if (c2 < N_NODES) v2 = *(const uint4*)(hs + ((size_t)c2 << 6) + dim0);
    if (c3 < N_NODES) v3 = *(const uint4*)(hs + ((size_t)c3 << 6) + dim0);
    accum8(v0, acc);
    accum8(v1, acc);
    accum8(v2, acc);
    accum8(v3, acc);
  }
  for (; e < e1; ++e) {
    unsigned c = (unsigned)col[e];
    uint4 v = make_uint4(0u, 0u, 0u, 0u);
    if (c < N_NODES) v = *(const uint4*)(hs + ((size_t)c << 6) + dim0);
    accum8(v, acc);
  }
}

// ---------------- SpMM layer-1: 8 lanes per node ----------------
__global__ __launch_bounds__(256) void spmm_kernel(const unsigned short* __restrict__ hs,
                                                   const int* __restrict__ rowptr,
                                                   const int* __restrict__ col,
                                                   const float* __restrict__ norm_in,
                                                   const float* __restrict__ b1f,
                                                   unsigned short* __restrict__ out) {
  int n = (int)(blockIdx.x * 32 + (threadIdx.x >> 3));
  int dim0 = ((int)threadIdx.x & 7) << 3;
  if (n >= N_NODES) return;
  int e0 = rowptr[n], e1 = rowptr[n + 1];
  if (e0 < 0) e0 = 0;
  if (e1 > N_EDGES) e1 = N_EDGES;
  float acc[8];
#pragma unroll
  for (int i = 0; i < 8; ++i) acc[i] = 0.f;
  spmm_gather8(hs, col, e0, e1, dim0, acc);
  float nin = norm_in[n];
  unsigned int pk[4];
#pragma unroll
  for (int i = 0; i < 4; ++i) {
    float vlo = fmaxf(acc[2 * i] * nin + b1f[dim0 + 2 * i], 0.f);
    float vhi = fmaxf(acc[2 * i + 1] * nin + b1f[dim0 + 2 * i + 1], 0.f);
    pk[i] = (unsigned int)f2bf(vlo) | ((unsigned int)f2bf(vhi) << 16);
  }
  *(uint4*)(out + ((size_t)n << 6) + dim0) = make_uint4(pk[0], pk[1], pk[2], pk[3]);
}

// ------- SpMM layer-2 fused with attention gate; 8 lanes per node ------------
__global__ __launch_bounds__(256) void spmm_attn_kernel(
    const unsigned short* __restrict__ hs,
    const int* __restrict__ rowptr, const int* __restrict__ col,
    const float* __restrict__ norm_in, const float* __restrict__ b2f,
    const float* __restrict__ attnWf, const float* __restrict__ attnbf,
    void* __restrict__ out_base, unsigned short* __restrict__ gated,
    const int* __restrict__ flag) {
  int mode = flag[0];
  int n = (int)(blockIdx.x * 32 + (threadIdx.x >> 3));
  int dim0 = ((int)threadIdx.x & 7) << 3;
  if (n >= N_NODES) return;
  int e0 = rowptr[n], e1 = rowptr[n + 1];
  if (e0 < 0) e0 = 0;
  if (e1 > N_EDGES) e1 = N_EDGES;
  float acc[8];
#pragma unroll
  for (int i = 0; i < 8; ++i) acc[i] = 0.f;
  spmm_gather8(hs, col, e0, e1, dim0, acc);
  float nin = norm_in[n];
  float vv[8];
  float p = 0.f;
#pragma unroll
  for (int i = 0; i < 8; ++i) {
    vv[i] = fmaxf(acc[i] * nin + b2f[dim0 + i], 0.f);  // h2[n][dim0+i]
    p += vv[i] * attnWf[dim0 + i];
  }
  // reduce across the 8 lanes of this node's group (lane bits 0..2)
#pragma unroll
  for (int m = 1; m <= 4; m <<= 1) p += __shfl_xor(p, m, 64);
  float logit = p + attnbf[0];
  float hwv = 1.f / (1.f + __expf(-logit));
  if ((threadIdx.x & 7) == 0) {
    if (mode) ((unsigned short*)out_base)[N_GRAPHS * N_CLASSES + n] = f2bf(hwv);
    else      ((float*)out_base)[N_GRAPHS * N_CLASSES + n] = hwv;
  }
  unsigned int pk[4];
#pragma unroll
  for (int i = 0; i < 4; ++i) {
    pk[i] = (unsigned int)f2bf(vv[2 * i] * hwv) |
            ((unsigned int)f2bf(vv[2 * i + 1] * hwv) << 16);
  }
  *(uint4*)(gated + ((size_t)n << 6) + dim0) = make_uint4(pk[0], pk[1], pk[2], pk[3]);
}

// -------- pool: 64 graphs x 32 slices, partial sums (occupancy fix) ----------
__global__ __launch_bounds__(256) void pool_kernel(const unsigned short* __restrict__ gated,
                                                   const int* __restrict__ gstart,
                                                   float* __restrict__ gpart) {
  int g = (int)blockIdx.x >> 5;         // graph
  int s = (int)blockIdx.x & 31;         // slice
  int dim = (int)threadIdx.x & 63;
  int rsel = (int)threadIdx.x >> 6;
  int r0 = gstart[g], r1 = gstart[g + 1];
  if (r0 < 0) r0 = 0;
  if (r1 > N_NODES) r1 = N_NODES;
  int len = r1 - r0;
  if (len < 0) len = 0;
  int a = r0 + (int)(((long long)len * s) >> 5);
  int bnd = r0 + (int)(((long long)len * (s + 1)) >> 5);
  float acc = 0.f;
  for (int r = a + rsel; r < bnd; r += 4)
    acc += bf2f(gated[((size_t)r << 6) + dim]);
  __shared__ float sm[256];
  sm[threadIdx.x] = acc;
  __syncthreads();
  if (threadIdx.x < 64)
    gpart[((size_t)blockIdx.x << 6) + dim] =
        sm[dim] + sm[64 + dim] + sm[128 + dim] + sm[192 + dim];
}

// -------- pool reduce: gsum[g][dim] = sum over 32 slice partials -------------
__global__ __launch_bounds__(64) void pool_reduce_kernel(const float* __restrict__ gpart,
                                                         float* __restrict__ gsum) {
  int g = (int)blockIdx.x;
  int dim = (int)threadIdx.x;
  float acc = 0.f;
#pragma unroll
  for (int s = 0; s < POOL_SLICES; ++s)
    acc += gpart[(((size_t)g << 5) + s << 6) + dim];
  gsum[((size_t)g << 6) + dim] = acc;
}

// ---------------- final: out[g][c] = (gsum[g]/cnt) . cls_W[:,c] + cls_b ----------
__global__ __launch_bounds__(640) void final_kernel(const float* __restrict__ gsum,
                                                    const int* __restrict__ gstart,
                                                    const float* __restrict__ clsWf,
                                                    const float* __restrict__ clsbf,
                                                    void* __restrict__ out_base,
                                                    const int* __restrict__ flag) {
  int mode = flag[0];
  int t = (int)threadIdx.x;
  if (t >= N_GRAPHS * N_CLASSES) return;
  int g = t / N_CLASSES, c = t - g * N_CLASSES;
  int cg = gstart[g + 1] - gstart[g];
  if (cg < 1) cg = 1;
  float inv = 1.f / (float)cg;
  float acc = 0.f;
#pragma unroll
  for (int d = 0; d < HID; ++d) acc += gsum[(g << 6) + d] * clsWf[d * N_CLASSES + c];
  float r = acc * inv + clsbf[c];
  if (mode) ((unsigned short*)out_base)[t] = f2bf(r);
  else      ((float*)out_base)[t] = r;
}

extern "C" void kernel_launch(void* const* d_in, const int* in_sizes, int n_in,
                              void* d_out, int out_size, void* d_ws, size_t ws_size,
                              hipStream_t stream) {
  const void* x     = d_in[0];
  const int*  ei    = (const int*)d_in[1];
  const int*  gid   = (const int*)d_in[2];
  const void* W1    = d_in[3];
  const void* b1    = d_in[4];
  const void* W2    = d_in[5];
  const void* b2    = d_in[6];
  const void* attnW = d_in[7];
  const void* attnb = d_in[8];
  const void* clsW  = d_in[9];
  const void* clsb  = d_in[10];

  if (ws_size < (size_t)WS_NEED) {
    fallback_kernel<<<(out_size + 255) / 256, 256, 0, stream>>>(
        (unsigned short*)d_out, out_size);
    return;
  }

  // ---- workspace layout (bytes). Every buffer fully written by a producer:
  // no zero-init kernel needed; safe under repeated launches.
  char* w = (char*)d_ws;
  int*   flag     = (int*)(w + 0);          //      64 (2 used, probe writes)
  int*   gstart   = (int*)(w + 64);         //     512 (gbound writes all)
  float* gsum     = (float*)(w + 576);      //   16384 (pool_reduce writes all)
  int*   bstart_d = (int*)(w + 16960);      //    1600 (392 used)
  int*   bstart_s = (int*)(w + 18560);      //    1600
  int*   blkhD    = (int*)(w + 20160);      //  306560 (196*391 ints)
  int*   blkhS    = (int*)(w + 326720);     //  306560
  int*   rowptr   = (int*)(w + 633280);     //  400064 (100001 used)
  float* norm_out = (float*)(w + 1033344);  //  400000
  float* norm_in  = (float*)(w + 1433344);  //  400000
  float* Wf1      = (float*)(w + 1833344);  //   32768
  float* Wf2      = (float*)(w + 1866112);  //   16384
  float* b1f      = (float*)(w + 1882496);  //     256
  float* b2f      = (float*)(w + 1882752);  //     256
  float* attnWf   = (float*)(w + 1883008);  //     256
  float* attnbf   = (float*)(w + 1883264);  //      64
  float* clsWf    = (float*)(w + 1883328);  //    2560
  float* clsbf    = (float*)(w + 1885888);  //      64 -> 1885952
  int*   colx     = (int*)(w + 1885952);    // 6400000 -> 8285952
  int2*  edst     = (int2*)(w + 8285952);   // 12800000 -> 21085952
  int*   esrc     = (int*)(w + 21085952);   // 6400000 -> 27485952
  // bufA aliases edst (dead after csr_kernel; gemm1 writes after).
  // bufB aliases esrc+tail (dead after csr_kernel; spmm1 writes after).
  unsigned short* bufA = (unsigned short*)(w + 8285952);   // 12800000
  unsigned short* bufB = (unsigned short*)(w + 21085952);  // 12800000 -> 33885952
  // gpart aliases blkhD/S (dead after part_scatter consumes the bases):
  // 64 graphs * 32 slices * 64 dims * 4B = 524288 <= 613120 available.
  float* gpart    = (float*)(w + 20160);

  probe_kernel<<<1, 256, 0, stream>>>((const unsigned short*)x, flag);
  wcvt_kernel<<<32, 256, 0, stream>>>(W1, W2, b1, b2, attnW, attnb, clsW, clsb,
                                      Wf1, Wf2, b1f, b2f, attnWf, attnbf, clsWf,
                                      clsbf, flag);

  // P1: per-chunk bucket histograms (no global atomics) + graph boundaries
  part_count_kernel<<<P1B + GB_BLOCKS, 256, 0, stream>>>(ei, blkhD, blkhS, gid, gstart);
  // P2: bucket scan; blkh* rewritten in place to per-(block,bucket) bases
  bucket_scan_kernel<<<2, 512, 0, stream>>>(blkhD, blkhS, bstart_d, bstart_s);
  // P3: partition edges into dst-bucket (pairs) and src-bucket (src-only) arrays
  part_scatter_kernel<<<P1B, 256, 0, stream>>>(ei, blkhD, blkhS, edst, esrc);
  // P4: per-bucket counting sort -> rowptr, col, norm_in | src counts -> norm_out
  csr_kernel<<<2 * NBUCK, 256, 0, stream>>>(edst, esrc, bstart_d, bstart_s,
                                            rowptr, colx, norm_in, norm_out);

  // layer 1: hs1 = (x @ W1) * norm_out  (scale fused; norms are ready)
  gemm_kernel<IN_DIM><<<GEMM_BLOCKS, 256, 0, stream>>>(x, Wf1, norm_out, bufA, flag);
  // layer 1 aggregation: h1 = relu(Agg(hs1) * norm_in + b1)
  spmm_kernel<<<SPMM_BLOCKS, 256, 0, stream>>>(bufA, rowptr, colx, norm_in, b1f, bufB);

  // layer 2: hs2 = (h1 @ W2) * norm_out ; agg + relu + attention -> gated rows
  gemm_kernel<HID><<<GEMM_BLOCKS, 256, 0, stream>>>(bufB, Wf2, norm_out, bufA, flag + 1);
  spmm_attn_kernel<<<SPMM_BLOCKS, 256, 0, stream>>>(
      bufA, rowptr, colx, norm_in, b2f, attnWf, attnbf, d_out, bufB, flag);

  // pooling: 2048 slice blocks -> partials (occupancy fix), then tiny reduce
  pool_kernel<<<N_GRAPHS * POOL_SLICES, 256, 0, stream>>>(bufB, gstart, gpart);
  pool_reduce_kernel<<<N_GRAPHS, 64, 0, stream>>>(gpart, gsum);
  final_kernel<<<1, 640, 0, stream>>>(gsum, gstart, clsWf, clsbf, d_out, flag);
}

// Round 5
// 274.670 us; speedup vs baseline: 1.9217x; 1.0841x over previous
//
#include <hip/hip_runtime.h>
#include <stdint.h>

// GNN: 2x GraphConv (norm='both') + attention gate + mean pooling + classifier.
// Round-12: gemm pair (45+22us) was VALU-latency-bound (VALUBusy 27%, occ 25%,
// MfmaUtil 0). Move both dense GEMMs to v_mfma_f32_16x16x32_bf16. Precision
// kept at fp32-equivalent via hi/lo bf16 split: W pre-split (Wh+Wl) in wcvt,
// stored fragment-ordered; fp32 x split on the fly (xh*Wh + xh*Wl + xl*Wh).
// gemm2's input is already bf16 -> 2 passes. Epilogue fuses norm_out scale.
// spmm 8-lane scheme, atomic-free bucket build, split pooling unchanged
// (528 -> 415.7 -> 322.9 -> 297.8us measured so far).

#define N_NODES   100000
#define N_EDGES   1600000
#define N_GRAPHS  64
#define IN_DIM    128
#define HID       64
#define N_CLASSES 10

#define NBUCK     391       // ceil(100000/256) buckets of 256 nodes
#define P1B       196       // partition chunk blocks
#define EPB       8192      // edges per chunk block (196*8192 >= 1.6M)
#define GB_BLOCKS 391       // ceil(100000/256)
#define MTILES    6250      // 100000 / 16 nodes per wave-tile
#define GEMM_BLOCKS 1563    // ceil(6250/4) wave-tiles per 256-thr block
#define SPMM_BLOCKS 3125    // 100000 / 32 nodes per block
#define POOL_SLICES 32      // blocks per graph in pooling
#define WS_NEED   33885952u

typedef __attribute__((ext_vector_type(8))) short short8v;
typedef __attribute__((ext_vector_type(4))) float f32x4;
typedef __bf16 bf16x8 __attribute__((ext_vector_type(8)));

__device__ __forceinline__ f32x4 mfma16(short8v a, short8v b, f32x4 c) {
  return __builtin_amdgcn_mfma_f32_16x16x32_bf16(
      __builtin_bit_cast(bf16x8, a), __builtin_bit_cast(bf16x8, b), c, 0, 0, 0);
}

__device__ __forceinline__ float bf2f(unsigned short u) {
  unsigned int v = ((unsigned int)u) << 16;
  float f;
  __builtin_memcpy(&f, &v, 4);
  return f;
}

__device__ __forceinline__ unsigned short f2bf(float f) {
  unsigned int x;
  __builtin_memcpy(&x, &f, 4);
  unsigned int lsb = (x >> 16) & 1u;
  x += 0x7fffu + lsb;  // round-to-nearest-even
  return (unsigned short)(x >> 16);
}

__device__ __forceinline__ void unpack_bf2(unsigned int u, float& lo, float& hi) {
  unsigned int a = u << 16;
  unsigned int b = u & 0xffff0000u;
  __builtin_memcpy(&lo, &a, 4);
  __builtin_memcpy(&hi, &b, 4);
}

// mode: 1 = tensors are bf16, 0 = tensors are fp32
__device__ __forceinline__ float ldf(const void* p, int i, int mode) {
  return mode ? bf2f(((const unsigned short*)p)[i]) : ((const float*)p)[i];
}

// ---------------- dtype probe ----------------
__global__ __launch_bounds__(256) void probe_kernel(const unsigned short* __restrict__ xu,
                                                    int* __restrict__ flag) {
  int tid = (int)threadIdx.x;
  unsigned u = xu[2 * tid];
  int e = (int)((u >> 7) & 0xFF);
  int ok = (e >= 110 && e <= 132) ? 1 : 0;
  unsigned long long m = __ballot(ok);
  __shared__ int cnt[4];
  if ((tid & 63) == 0) cnt[tid >> 6] = __popcll(m);
  __syncthreads();
  if (tid == 0) {
    flag[0] = (cnt[0] + cnt[1] + cnt[2] + cnt[3] > 128) ? 1 : 0;
    flag[1] = 1;
  }
}

// ---------------- fallback (ws too small): deterministic zero output ----------
__global__ __launch_bounds__(256) void fallback_kernel(unsigned short* __restrict__ out,
                                                       int n) {
  int i = blockIdx.x * 256 + threadIdx.x;
  if (i < n) out[i] = 0;
}

// ------- params -> fp32 biases + fragment-ordered hi/lo bf16 weights ---------
// Fragment entry (tile = kt*4+ct, lane): 8 bf16 of W[k = kt*32+(lane>>4)*8+j]
// [d = ct*16+(lane&15)], contiguous 16B so gemm loads one uint4 per frag.
__global__ __launch_bounds__(256) void wcvt_kernel(
    const void* __restrict__ W1, const void* __restrict__ W2,
    const void* __restrict__ b1, const void* __restrict__ b2,
    const void* __restrict__ attnW, const void* __restrict__ attnb,
    const void* __restrict__ clsW, const void* __restrict__ clsb,
    unsigned short* __restrict__ W1hf, unsigned short* __restrict__ W1lf,
    unsigned short* __restrict__ W2hf, unsigned short* __restrict__ W2lf,
    float* __restrict__ b1f, float* __restrict__ b2f,
    float* __restrict__ attnWf, float* __restrict__ attnbf,
    float* __restrict__ clsWf, float* __restrict__ clsbf,
    const int* __restrict__ flag) {
  int mode = flag[0];
  int i = blockIdx.x * 256 + threadIdx.x;
  if (i < 1024) {
    // W1 fragments: 16 tiles (4 kt x 4 ct) x 64 lanes
    int tile = i >> 6, lane = i & 63;
    int kt = tile >> 2, ct = tile & 3;
#pragma unroll
    for (int j = 0; j < 8; ++j) {
      int k = kt * 32 + ((lane >> 4) << 3) + j;
      int d = (ct << 4) + (lane & 15);
      float v = ldf(W1, k * HID + d, mode);
      unsigned short h = f2bf(v);
      unsigned short l = f2bf(v - bf2f(h));
      W1hf[i * 8 + j] = h;
      W1lf[i * 8 + j] = l;
    }
  } else if (i < 1536) {
    // W2 fragments: 8 tiles (2 kt x 4 ct) x 64 lanes
    int ii = i - 1024;
    int tile = ii >> 6, lane = ii & 63;
    int kt = tile >> 2, ct = tile & 3;
#pragma unroll
    for (int j = 0; j < 8; ++j) {
      int k = kt * 32 + ((lane >> 4) << 3) + j;
      int d = (ct << 4) + (lane & 15);
      float v = ldf(W2, k * HID + d, mode);
      unsigned short h = f2bf(v);
      unsigned short l = f2bf(v - bf2f(h));
      W2hf[ii * 8 + j] = h;
      W2lf[ii * 8 + j] = l;
    }
  }
  if (i < HID) {
    b1f[i] = ldf(b1, i, mode);
    b2f[i] = ldf(b2, i, mode);
    attnWf[i] = ldf(attnW, i, mode);
  }
  if (i == 0) attnbf[0] = ldf(attnb, 0, mode);
  if (i < HID * N_CLASSES) clsWf[i] = ldf(clsW, i, mode);
  if (i < N_CLASSES) clsbf[i] = ldf(clsb, i, mode);
}

// =============== P1: per-chunk bucket histograms (dst & src) | gbound ========
__global__ __launch_bounds__(256) void part_count_kernel(
    const int* __restrict__ ei, int* __restrict__ blkhistD,
    int* __restrict__ blkhistS,
    const int* __restrict__ gid, int* __restrict__ gstart) {
  int b = (int)blockIdx.x;
  int t = (int)threadIdx.x;
  if (b < P1B) {
    __shared__ int hD[NBUCK];
    __shared__ int hS[NBUCK];
    for (int i = t; i < NBUCK; i += 256) { hD[i] = 0; hS[i] = 0; }
    __syncthreads();
    int base_e = b * EPB;
    for (int s = 0; s < EPB / 1024; ++s) {
      int e4 = base_e + s * 1024 + t * 4;
      if (e4 < N_EDGES) {
        int4 s4 = *(const int4*)(ei + e4);
        int4 d4 = *(const int4*)(ei + N_EDGES + e4);
        int ss[4] = {s4.x, s4.y, s4.z, s4.w};
        int dd[4] = {d4.x, d4.y, d4.z, d4.w};
#pragma unroll
        for (int j = 0; j < 4; ++j) {
          if ((unsigned)ss[j] < N_NODES) atomicAdd(&hS[ss[j] >> 8], 1);
          if ((unsigned)dd[j] < N_NODES) atomicAdd(&hD[dd[j] >> 8], 1);
        }
      }
    }
    __syncthreads();
    for (int i = t; i < NBUCK; i += 256) {
      blkhistD[b * NBUCK + i] = hD[i];
      blkhistS[b * NBUCK + i] = hS[i];
    }
  } else {
    // ---- gbound part ----
    int bb = b - P1B;
    int n = bb * 256 + t;
    if (n >= N_NODES) return;
    int gc = gid[n] & (N_GRAPHS - 1);
    if (n == 0) {
      for (int g = 0; g <= gc; ++g) gstart[g] = 0;
    } else {
      int gp = gid[n - 1] & (N_GRAPHS - 1);
      for (int g = gp + 1; g <= gc; ++g) gstart[g] = n;
    }
    if (n == N_NODES - 1) {
      for (int g = gc + 1; g <= N_GRAPHS; ++g) gstart[g] = N_NODES;
    }
  }
}

// =============== P2: bucket totals scan + in-place per-block bases ===========
__global__ __launch_bounds__(512) void bucket_scan_kernel(
    int* __restrict__ blkhistD, int* __restrict__ blkhistS,
    int* __restrict__ bstart_d, int* __restrict__ bstart_s) {
  int* hist = (blockIdx.x == 0) ? blkhistD : blkhistS;
  int* bst  = (blockIdx.x == 0) ? bstart_d : bstart_s;
  int u = (int)threadIdx.x;
  int tot = 0;
  if (u < NBUCK) {
    for (int blk = 0; blk < P1B; ++blk) tot += hist[blk * NBUCK + u];
  }
  __shared__ int smA[512];
  __shared__ int smB[512];
  smA[u] = tot;
  __syncthreads();
  int* a = smA;
  int* bq = smB;
  for (int off = 1; off < 512; off <<= 1) {
    int v = a[u];
    if (u >= off) v += a[u - off];
    bq[u] = v;
    __syncthreads();
    int* tmp = a; a = bq; bq = tmp;
  }
  int excl = a[u] - tot;
  if (u <= NBUCK) bst[u] = excl;  // u==NBUCK: tot==0 -> excl == total
  if (u < NBUCK) {
    int off2 = excl;
    for (int blk = 0; blk < P1B; ++blk) {
      int h = hist[blk * NBUCK + u];
      hist[blk * NBUCK + u] = off2;
      off2 += h;
    }
  }
}

// =============== P3: scatter edges into bucket-partitioned arrays ============
__global__ __launch_bounds__(256) void part_scatter_kernel(
    const int* __restrict__ ei, const int* __restrict__ blkbaseD,
    const int* __restrict__ blkbaseS,
    int2* __restrict__ edst, int* __restrict__ esrc) {
  __shared__ int cD[NBUCK];
  __shared__ int cS[NBUCK];
  int b = (int)blockIdx.x;
  int t = (int)threadIdx.x;
  for (int i = t; i < NBUCK; i += 256) {
    cD[i] = blkbaseD[b * NBUCK + i];
    cS[i] = blkbaseS[b * NBUCK + i];
  }
  __syncthreads();
  int base_e = b * EPB;
  for (int s = 0; s < EPB / 1024; ++s) {
    int e4 = base_e + s * 1024 + t * 4;
    if (e4 < N_EDGES) {
      int4 s4 = *(const int4*)(ei + e4);
      int4 d4 = *(const int4*)(ei + N_EDGES + e4);
      int ss[4] = {s4.x, s4.y, s4.z, s4.w};
      int dd[4] = {d4.x, d4.y, d4.z, d4.w};
#pragma unroll
      for (int j = 0; j < 4; ++j) {
        if ((unsigned)ss[j] < N_NODES) {
          int slot = atomicAdd(&cS[ss[j] >> 8], 1);
          esrc[slot] = ss[j];
        }
        if ((unsigned)dd[j] < N_NODES) {
          int slot = atomicAdd(&cD[dd[j] >> 8], 1);
          edst[slot] = make_int2(ss[j], dd[j]);
        }
      }
    }
  }
}

// =============== P4: per-bucket counting sort -> rowptr/col/norms ============
__global__ __launch_bounds__(256) void csr_kernel(
    const int2* __restrict__ edst, const int* __restrict__ esrc,
    const int* __restrict__ bstart_d, const int* __restrict__ bstart_s,
    int* __restrict__ rowptr, int* __restrict__ colx,
    float* __restrict__ norm_in, float* __restrict__ norm_out) {
  __shared__ int lc[256];
  __shared__ int smA[256];
  __shared__ int smB[256];
  int b = (int)blockIdx.x;
  int t = (int)threadIdx.x;
  if (b < NBUCK) {
    int node0 = b << 8;
    int base = bstart_d[b];
    int end  = bstart_d[b + 1];
    lc[t] = 0;
    __syncthreads();
    for (int i = base + t; i < end; i += 256) {
      int2 p = edst[i];
      atomicAdd(&lc[p.y - node0], 1);
    }
    __syncthreads();
    int my = lc[t];
    smA[t] = my;
    __syncthreads();
    int* a = smA;
    int* bq = smB;
    for (int off = 1; off < 256; off <<= 1) {
      int v = a[t];
      if (t >= off) v += a[t - off];
      bq[t] = v;
      __syncthreads();
      int* tmp = a; a = bq; bq = tmp;
    }
    int excl = a[t] - my;
    int n = node0 + t;
    if (n <= N_NODES) rowptr[n] = base + excl;
    if (n < N_NODES) {
      int c = my < 1 ? 1 : my;
      norm_in[n] = rsqrtf((float)c);
    }
    __syncthreads();
    lc[t] = base + excl;  // per-node cursor
    __syncthreads();
    for (int i = base + t; i < end; i += 256) {
      int2 p = edst[i];
      int slot = atomicAdd(&lc[p.y - node0], 1);
      colx[slot] = p.x;
    }
  } else {
    int bb = b - NBUCK;
    int node0 = bb << 8;
    int base = bstart_s[bb];
    int end  = bstart_s[bb + 1];
    lc[t] = 0;
    __syncthreads();
    for (int i = base + t; i < end; i += 256) {
      atomicAdd(&lc[esrc[i] - node0], 1);
    }
    __syncthreads();
    int n = node0 + t;
    if (n < N_NODES) {
      int c = lc[t] < 1 ? 1 : lc[t];
      norm_out[n] = rsqrtf((float)c);
    }
  }
}

// ====== MFMA GEMM: out[n][d] = bf16((A[n,:] . W[:,d]) * norm_out[n]) =========
// Wave = one 16-node x 64-dim tile. A-frag: lane holds A[lane&15][kg*8+j].
// B-frag: lane holds W[kg*8+j][lane&15] (pre-swizzled by wcvt). C/D: col=
// lane&15, row=(lane>>4)*4+reg (HW-verified layout). fp32 A split into hi/lo
// bf16 (3 mfma passes); bf16 A uses 2 passes (W hi/lo).
template <int K>
__global__ __launch_bounds__(256) void gemm_mfma_kernel(
    const void* __restrict__ A, const unsigned short* __restrict__ Whf,
    const unsigned short* __restrict__ Wlf, const float* __restrict__ norm_out,
    unsigned short* __restrict__ out, const int* __restrict__ flag) {
  int mode = flag[0];
  int mtile = (int)blockIdx.x * 4 + ((int)threadIdx.x >> 6);
  if (mtile >= MTILES) return;
  int n0 = mtile << 4;
  int lane = (int)threadIdx.x & 63;
  int row = lane & 15;
  int kg = lane >> 4;
  f32x4 acc0 = {0.f, 0.f, 0.f, 0.f};
  f32x4 acc1 = {0.f, 0.f, 0.f, 0.f};
  f32x4 acc2 = {0.f, 0.f, 0.f, 0.f};
  f32x4 acc3 = {0.f, 0.f, 0.f, 0.f};
  const short8v* whb0 = (const short8v*)Whf + lane;
  const short8v* wlb0 = (const short8v*)Wlf + lane;
  if (mode) {
    const unsigned short* xr = (const unsigned short*)A + (size_t)(n0 + row) * K + (kg << 3);
#pragma unroll
    for (int kt = 0; kt < K / 32; ++kt) {
      uint4 va = *(const uint4*)(xr + kt * 32);
      short8v xh = __builtin_bit_cast(short8v, va);
      const short8v* wh = whb0 + (size_t)(kt * 4) * 64;
      const short8v* wl = wlb0 + (size_t)(kt * 4) * 64;
      acc0 = mfma16(xh, wh[0], acc0);
      acc1 = mfma16(xh, wh[64], acc1);
      acc2 = mfma16(xh, wh[128], acc2);
      acc3 = mfma16(xh, wh[192], acc3);
      acc0 = mfma16(xh, wl[0], acc0);
      acc1 = mfma16(xh, wl[64], acc1);
      acc2 = mfma16(xh, wl[128], acc2);
      acc3 = mfma16(xh, wl[192], acc3);
    }
  } else {
    const float* xr = (const float*)A + (size_t)(n0 + row) * K + (kg << 3);
#pragma unroll
    for (int kt = 0; kt < K / 32; ++kt) {
      float4 a0 = *(const float4*)(xr + kt * 32);
      float4 a1 = *(const float4*)(xr + kt * 32 + 4);
      float xv[8] = {a0.x, a0.y, a0.z, a0.w, a1.x, a1.y, a1.z, a1.w};
      short8v xh, xl;
#pragma unroll
      for (int j = 0; j < 8; ++j) {
        unsigned short h = f2bf(xv[j]);
        unsigned short l = f2bf(xv[j] - bf2f(h));
        xh[j] = (short)h;
        xl[j] = (short)l;
      }
      const short8v* wh = whb0 + (size_t)(kt * 4) * 64;
      const short8v* wl = wlb0 + (size_t)(kt * 4) * 64;
      acc0 = mfma16(xh, wh[0], acc0);
      acc1 = mfma16(xh, wh[64], acc1);
      acc2 = mfma16(xh, wh[128], acc2);
      acc3 = mfma16(xh, wh[192], acc3);
      acc0 = mfma16(xh, wl[0], acc0);
      acc1 = mfma16(xh, wl[64], acc1);
      acc2 = mfma16(xh, wl[128], acc2);
      acc3 = mfma16(xh, wl[192], acc3);
      acc0 = mfma16(xl, wh[0], acc0);
      acc1 = mfma16(xl, wh[64], acc1);
      acc2 = mfma16(xl, wh[128], acc2);
      acc3 = mfma16(xl, wh[192], acc3);
    }
  }
  // epilogue: scale rows by norm_out, store bf16
  int col = lane & 15;
#pragma unroll
  for (int i = 0; i < 4; ++i) {
    int n = n0 + (kg << 2) + i;
    float s = norm_out[n];
    size_t rb = (size_t)n << 6;
    out[rb + col]      = f2bf(acc0[i] * s);
    out[rb + 16 + col] = f2bf(acc1[i] * s);
    out[rb + 32 + col] = f2bf(acc2[i] * s);
    out[rb + 48 + col] = f2bf(acc3[i] * s);
  }
}

// ---------------- SpMM core: 8 lanes per node, serial edges, no fold ---------
__device__ __forceinline__ void accum8(uint4 v, float acc[8]) {
  float lo, hi;
  unpack_bf2(v.x, lo, hi); acc[0] += lo; acc[1] += hi;
  unpack_bf2(v.y, lo, hi); acc[2] += lo; acc[3] += hi;
  unpack_bf2(v.z, lo, hi); acc[4] += lo; acc[5] += hi;
  unpack_bf2(v.w, lo, hi); acc[6] += lo; acc[7] += hi;
}

__device__ __forceinline__ void spmm_gather8(const unsigned short* __restrict__ hs,
                                             const int* __restrict__ col,
                                             int e0, int e1, int dim0,
                                             float acc[8]) {
  int e = e0;
  for (; e + 4 <= e1; e += 4) {
    unsigned c0 = (unsigned)col[e];
    unsigned c1 = (unsigned)col[e + 1];
    unsigned c2 = (unsigned)col[e + 2];
    unsigned c3 = (unsigned)col[e + 3];
    uint4 v0 = make_uint4(0u, 0u, 0u, 0u);
    uint4 v1 = v0, v2 = v0, v3 = v0;
    if (c0 < N_NODES) v0 = *(const uint4*)(hs + ((size_t)c0 << 6) + dim0);
    if (c1 < N_NODES) v1 = *(const uint4*)(hs + ((size_t)c1 << 6) + dim0);
    if (c2 < N_NODES) v2 = *(const uint4*)(hs + ((size_t)c2 << 6) + dim0);
    if (c3 < N_NODES) v3 = *(const uint4*)(hs + ((size_t)c3 << 6) + dim0);
    accum8(v0, acc);
    accum8(v1, acc);
    accum8(v2, acc);
    accum8(v3, acc);
  }
  for (; e < e1; ++e) {
    unsigned c = (unsigned)col[e];
    uint4 v = make_uint4(0u, 0u, 0u, 0u);
    if (c < N_NODES) v = *(const uint4*)(hs + ((size_t)c << 6) + dim0);
    accum8(v, acc);
  }
}

// ---------------- SpMM layer-1: 8 lanes per node ----------------
__global__ __launch_bounds__(256) void spmm_kernel(const unsigned short* __restrict__ hs,
                                                   const int* __restrict__ rowptr,
                                                   const int* __restrict__ col,
                                                   const float* __restrict__ norm_in,
                                                   const float* __restrict__ b1f,
                                                   unsigned short* __restrict__ out) {
  int n = (int)(blockIdx.x * 32 + (threadIdx.x >> 3));
  int dim0 = ((int)threadIdx.x & 7) << 3;
  if (n >= N_NODES) return;
  int e0 = rowptr[n], e1 = rowptr[n + 1];
  if (e0 < 0) e0 = 0;
  if (e1 > N_EDGES) e1 = N_EDGES;
  float acc[8];
#pragma unroll
  for (int i = 0; i < 8; ++i) acc[i] = 0.f;
  spmm_gather8(hs, col, e0, e1, dim0, acc);
  float nin = norm_in[n];
  unsigned int pk[4];
#pragma unroll
  for (int i = 0; i < 4; ++i) {
    float vlo = fmaxf(acc[2 * i] * nin + b1f[dim0 + 2 * i], 0.f);
    float vhi = fmaxf(acc[2 * i + 1] * nin + b1f[dim0 + 2 * i + 1], 0.f);
    pk[i] = (unsigned int)f2bf(vlo) | ((unsigned int)f2bf(vhi) << 16);
  }
  *(uint4*)(out + ((size_t)n << 6) + dim0) = make_uint4(pk[0], pk[1], pk[2], pk[3]);
}

// ------- SpMM layer-2 fused with attention gate; 8 lanes per node ------------
__global__ __launch_bounds__(256) void spmm_attn_kernel(
    const unsigned short* __restrict__ hs,
    const int* __restrict__ rowptr, const int* __restrict__ col,
    const float* __restrict__ norm_in, const float* __restrict__ b2f,
    const float* __restrict__ attnWf, const float* __restrict__ attnbf,
    void* __restrict__ out_base, unsigned short* __restrict__ gated,
    const int* __restrict__ flag) {
  int mode = flag[0];
  int n = (int)(blockIdx.x * 32 + (threadIdx.x >> 3));
  int dim0 = ((int)threadIdx.x & 7) << 3;
  if (n >= N_NODES) return;
  int e0 = rowptr[n], e1 = rowptr[n + 1];
  if (e0 < 0) e0 = 0;
  if (e1 > N_EDGES) e1 = N_EDGES;
  float acc[8];
#pragma unroll
  for (int i = 0; i < 8; ++i) acc[i] = 0.f;
  spmm_gather8(hs, col, e0, e1, dim0, acc);
  float nin = norm_in[n];
  float vv[8];
  float p = 0.f;
#pragma unroll
  for (int i = 0; i < 8; ++i) {
    vv[i] = fmaxf(acc[i] * nin + b2f[dim0 + i], 0.f);  // h2[n][dim0+i]
    p += vv[i] * attnWf[dim0 + i];
  }
  // reduce across the 8 lanes of this node's group (lane bits 0..2)
#pragma unroll
  for (int m = 1; m <= 4; m <<= 1) p += __shfl_xor(p, m, 64);
  float logit = p + attnbf[0];
  float hwv = 1.f / (1.f + __expf(-logit));
  if ((threadIdx.x & 7) == 0) {
    if (mode) ((unsigned short*)out_base)[N_GRAPHS * N_CLASSES + n] = f2bf(hwv);
    else      ((float*)out_base)[N_GRAPHS * N_CLASSES + n] = hwv;
  }
  unsigned int pk[4];
#pragma unroll
  for (int i = 0; i < 4; ++i) {
    pk[i] = (unsigned int)f2bf(vv[2 * i] * hwv) |
            ((unsigned int)f2bf(vv[2 * i + 1] * hwv) << 16);
  }
  *(uint4*)(gated + ((size_t)n << 6) + dim0) = make_uint4(pk[0], pk[1], pk[2], pk[3]);
}

// -------- pool: 64 graphs x 32 slices, partial sums (occupancy fix) ----------
__global__ __launch_bounds__(256) void pool_kernel(const unsigned short* __restrict__ gated,
                                                   const int* __restrict__ gstart,
                                                   float* __restrict__ gpart) {
  int g = (int)blockIdx.x >> 5;         // graph
  int s = (int)blockIdx.x & 31;         // slice
  int dim = (int)threadIdx.x & 63;
  int rsel = (int)threadIdx.x >> 6;
  int r0 = gstart[g], r1 = gstart[g + 1];
  if (r0 < 0) r0 = 0;
  if (r1 > N_NODES) r1 = N_NODES;
  int len = r1 - r0;
  if (len < 0) len = 0;
  int a = r0 + (int)(((long long)len * s) >> 5);
  int bnd = r0 + (int)(((long long)len * (s + 1)) >> 5);
  float acc = 0.f;
  for (int r = a + rsel; r < bnd; r += 4)
    acc += bf2f(gated[((size_t)r << 6) + dim]);
  __shared__ float sm[256];
  sm[threadIdx.x] = acc;
  __syncthreads();
  if (threadIdx.x < 64)
    gpart[((size_t)blockIdx.x << 6) + dim] =
        sm[dim] + sm[64 + dim] + sm[128 + dim] + sm[192 + dim];
}

// -------- pool reduce: gsum[g][dim] = sum over 32 slice partials -------------
__global__ __launch_bounds__(64) void pool_reduce_kernel(const float* __restrict__ gpart,
                                                         float* __restrict__ gsum) {
  int g = (int)blockIdx.x;
  int dim = (int)threadIdx.x;
  float acc = 0.f;
#pragma unroll
  for (int s = 0; s < POOL_SLICES; ++s)
    acc += gpart[(((size_t)g << 5) + s << 6) + dim];
  gsum[((size_t)g << 6) + dim] = acc;
}

// ---------------- final: out[g][c] = (gsum[g]/cnt) . cls_W[:,c] + cls_b ----------
__global__ __launch_bounds__(640) void final_kernel(const float* __restrict__ gsum,
                                                    const int* __restrict__ gstart,
                                                    const float* __restrict__ clsWf,
                                                    const float* __restrict__ clsbf,
                                                    void* __restrict__ out_base,
                                                    const int* __restrict__ flag) {
  int mode = flag[0];
  int t = (int)threadIdx.x;
  if (t >= N_GRAPHS * N_CLASSES) return;
  int g = t / N_CLASSES, c = t - g * N_CLASSES;
  int cg = gstart[g + 1] - gstart[g];
  if (cg < 1) cg = 1;
  float inv = 1.f / (float)cg;
  float acc = 0.f;
#pragma unroll
  for (int d = 0; d < HID; ++d) acc += gsum[(g << 6) + d] * clsWf[d * N_CLASSES + c];
  float r = acc * inv + clsbf[c];
  if (mode) ((unsigned short*)out_base)[t] = f2bf(r);
  else      ((float*)out_base)[t] = r;
}

extern "C" void kernel_launch(void* const* d_in, const int* in_sizes, int n_in,
                              void* d_out, int out_size, void* d_ws, size_t ws_size,
                              hipStream_t stream) {
  const void* x     = d_in[0];
  const int*  ei    = (const int*)d_in[1];
  const int*  gid   = (const int*)d_in[2];
  const void* W1    = d_in[3];
  const void* b1    = d_in[4];
  const void* W2    = d_in[5];
  const void* b2    = d_in[6];
  const void* attnW = d_in[7];
  const void* attnb = d_in[8];
  const void* clsW  = d_in[9];
  const void* clsb  = d_in[10];

  if (ws_size < (size_t)WS_NEED) {
    fallback_kernel<<<(out_size + 255) / 256, 256, 0, stream>>>(
        (unsigned short*)d_out, out_size);
    return;
  }

  // ---- workspace layout (bytes). Every buffer fully written by a producer:
  // no zero-init kernel needed; safe under repeated launches.
  char* w = (char*)d_ws;
  int*   flag     = (int*)(w + 0);          //      64 (2 used, probe writes)
  int*   gstart   = (int*)(w + 64);         //     512 (gbound writes all)
  float* gsum     = (float*)(w + 576);      //   16384 (pool_reduce writes all)
  int*   bstart_d = (int*)(w + 16960);      //    1600 (392 used)
  int*   bstart_s = (int*)(w + 18560);      //    1600
  int*   blkhD    = (int*)(w + 20160);      //  306560 (196*391 ints)
  int*   blkhS    = (int*)(w + 326720);     //  306560
  int*   rowptr   = (int*)(w + 633280);     //  400064 (100001 used)
  float* norm_out = (float*)(w + 1033344);  //  400000
  float* norm_in  = (float*)(w + 1433344);  //  400000
  unsigned short* W1hf = (unsigned short*)(w + 1833344);  // 16384
  unsigned short* W1lf = (unsigned short*)(w + 1849728);  // 16384
  unsigned short* W2hf = (unsigned short*)(w + 1866112);  //  8192
  unsigned short* W2lf = (unsigned short*)(w + 1874304);  //  8192 -> 1882496
  float* b1f      = (float*)(w + 1882496);  //     256
  float* b2f      = (float*)(w + 1882752);  //     256
  float* attnWf   = (float*)(w + 1883008);  //     256
  float* attnbf   = (float*)(w + 1883264);  //      64
  float* clsWf    = (float*)(w + 1883328);  //    2560
  float* clsbf    = (float*)(w + 1885888);  //      64 -> 1885952
  int*   colx     = (int*)(w + 1885952);    // 6400000 -> 8285952
  int2*  edst     = (int2*)(w + 8285952);   // 12800000 -> 21085952
  int*   esrc     = (int*)(w + 21085952);   // 6400000 -> 27485952
  // bufA aliases edst (dead after csr_kernel; gemm1 writes after).
  // bufB aliases esrc+tail (dead after csr_kernel; spmm1 writes after).
  unsigned short* bufA = (unsigned short*)(w + 8285952);   // 12800000
  unsigned short* bufB = (unsigned short*)(w + 21085952);  // 12800000 -> 33885952
  // gpart aliases blkhD/S (dead after part_scatter consumes the bases):
  // 64 graphs * 32 slices * 64 dims * 4B = 524288 <= 613120 available.
  float* gpart    = (float*)(w + 20160);

  probe_kernel<<<1, 256, 0, stream>>>((const unsigned short*)x, flag);
  wcvt_kernel<<<32, 256, 0, stream>>>(W1, W2, b1, b2, attnW, attnb, clsW, clsb,
                                      W1hf, W1lf, W2hf, W2lf, b1f, b2f, attnWf,
                                      attnbf, clsWf, clsbf, flag);

  // P1: per-chunk bucket histograms (no global atomics) + graph boundaries
  part_count_kernel<<<P1B + GB_BLOCKS, 256, 0, stream>>>(ei, blkhD, blkhS, gid, gstart);
  // P2: bucket scan; blkh* rewritten in place to per-(block,bucket) bases
  bucket_scan_kernel<<<2, 512, 0, stream>>>(blkhD, blkhS, bstart_d, bstart_s);
  // P3: partition edges into dst-bucket (pairs) and src-bucket (src-only) arrays
  part_scatter_kernel<<<P1B, 256, 0, stream>>>(ei, blkhD, blkhS, edst, esrc);
  // P4: per-bucket counting sort -> rowptr, col, norm_in | src counts -> norm_out
  csr_kernel<<<2 * NBUCK, 256, 0, stream>>>(edst, esrc, bstart_d, bstart_s,
                                            rowptr, colx, norm_in, norm_out);

  // layer 1: hs1 = (x @ W1) * norm_out  (MFMA, hi/lo split, scale fused)
  gemm_mfma_kernel<IN_DIM><<<GEMM_BLOCKS, 256, 0, stream>>>(
      x, W1hf, W1lf, norm_out, bufA, flag);
  // layer 1 aggregation: h1 = relu(Agg(hs1) * norm_in + b1)
  spmm_kernel<<<SPMM_BLOCKS, 256, 0, stream>>>(bufA, rowptr, colx, norm_in, b1f, bufB);

  // layer 2: hs2 = (h1 @ W2) * norm_out (MFMA; input already bf16 via flag+1)
  gemm_mfma_kernel<HID><<<GEMM_BLOCKS, 256, 0, stream>>>(
      bufB, W2hf, W2lf, norm_out, bufA, flag + 1);
  spmm_attn_kernel<<<SPMM_BLOCKS, 256, 0, stream>>>(
      bufA, rowptr, colx, norm_in, b2f, attnWf, attnbf, d_out, bufB, flag);

  // pooling: 2048 slice blocks -> partials (occupancy fix), then tiny reduce
  pool_kernel<<<N_GRAPHS * POOL_SLICES, 256, 0, stream>>>(bufB, gstart, gpart);
  pool_reduce_kernel<<<N_GRAPHS, 64, 0, stream>>>(gpart, gsum);
  final_kernel<<<1, 640, 0, stream>>>(gsum, gstart, clsWf, clsbf, d_out, flag);
}

// Round 6
// 270.047 us; speedup vs baseline: 1.9546x; 1.0171x over previous
//
#include <hip/hip_runtime.h>
#include <stdint.h>

// GNN: 2x GraphConv (norm='both') + attention gate + mean pooling + classifier.
// Round-13: profile is flat (all our dispatches < 40us; top-5 is harness fill).
// Remaining cost = serialization + launch gaps of 13 small kernels. Changes:
//  - FAT-A: part_count | gemm1_raw (unscaled x@W1, MFMA) | gbound co-dispatch;
//    gemm1 no longer depends on the build chain.
//  - norm_out scale folded into spmm1 gather as v_fma (same inst count as add).
//  - edst packed (src<<8 | dst&255) -> 6.4MB, freeing 12.8MB so bufA can be
//    live during the build at the same WS_NEED.
//  - probe merged into wcvt (self-probe); pool_reduce merged into final (LDS).
// 13 -> 10 dispatches. History: 528 -> 415.7 -> 322.9 -> 297.8 -> 274.7us.

#define N_NODES   100000
#define N_EDGES   1600000
#define N_GRAPHS  64
#define IN_DIM    128
#define HID       64
#define N_CLASSES 10

#define NBUCK     391       // ceil(100000/256) buckets of 256 nodes
#define P1B       196       // partition chunk blocks
#define EPB       8192      // edges per chunk block (196*8192 >= 1.6M)
#define GB_BLOCKS 391       // ceil(100000/256)
#define MTILES    6250      // 100000 / 16 nodes per wave-tile
#define GEMM_BLOCKS 1563    // ceil(6250/4) wave-tiles per 256-thr block
#define SPMM_BLOCKS 3125    // 100000 / 32 nodes per block
#define POOL_SLICES 32      // blocks per graph in pooling
#define WS_NEED   33885952u

typedef __attribute__((ext_vector_type(8))) short short8v;
typedef __attribute__((ext_vector_type(4))) float f32x4;
typedef __bf16 bf16x8 __attribute__((ext_vector_type(8)));

__device__ __forceinline__ f32x4 mfma16(short8v a, short8v b, f32x4 c) {
  return __builtin_amdgcn_mfma_f32_16x16x32_bf16(
      __builtin_bit_cast(bf16x8, a), __builtin_bit_cast(bf16x8, b), c, 0, 0, 0);
}

__device__ __forceinline__ float bf2f(unsigned short u) {
  unsigned int v = ((unsigned int)u) << 16;
  float f;
  __builtin_memcpy(&f, &v, 4);
  return f;
}

__device__ __forceinline__ unsigned short f2bf(float f) {
  unsigned int x;
  __builtin_memcpy(&x, &f, 4);
  unsigned int lsb = (x >> 16) & 1u;
  x += 0x7fffu + lsb;  // round-to-nearest-even
  return (unsigned short)(x >> 16);
}

__device__ __forceinline__ void unpack_bf2(unsigned int u, float& lo, float& hi) {
  unsigned int a = u << 16;
  unsigned int b = u & 0xffff0000u;
  __builtin_memcpy(&lo, &a, 4);
  __builtin_memcpy(&hi, &b, 4);
}

// mode: 1 = tensors are bf16, 0 = tensors are fp32
__device__ __forceinline__ float ldf(const void* p, int i, int mode) {
  return mode ? bf2f(((const unsigned short*)p)[i]) : ((const float*)p)[i];
}

// ---------------- fallback (ws too small): deterministic zero output ----------
__global__ __launch_bounds__(256) void fallback_kernel(unsigned short* __restrict__ out,
                                                       int n) {
  int i = blockIdx.x * 256 + threadIdx.x;
  if (i < n) out[i] = 0;
}

// ------- wcvt (with per-block self-probe of x's dtype) -----------------------
// Fragment entry (tile = kt*4+ct, lane): 8 bf16 of W[k = kt*32+(lane>>4)*8+j]
// [d = ct*16+(lane&15)], contiguous 16B so gemm loads one uint4 per frag.
__global__ __launch_bounds__(256) void wcvt_kernel(
    const unsigned short* __restrict__ xu,
    const void* __restrict__ W1, const void* __restrict__ W2,
    const void* __restrict__ b1, const void* __restrict__ b2,
    const void* __restrict__ attnW, const void* __restrict__ attnb,
    const void* __restrict__ clsW, const void* __restrict__ clsb,
    unsigned short* __restrict__ W1hf, unsigned short* __restrict__ W1lf,
    unsigned short* __restrict__ W2hf, unsigned short* __restrict__ W2lf,
    float* __restrict__ b1f, float* __restrict__ b2f,
    float* __restrict__ attnWf, float* __restrict__ attnbf,
    float* __restrict__ clsWf, float* __restrict__ clsbf,
    int* __restrict__ flag) {
  // ---- self-probe: every block derives mode from x's exponent pattern ----
  __shared__ int cnt[4];
  __shared__ int smode;
  int tid = (int)threadIdx.x;
  unsigned u = xu[2 * tid];
  int e = (int)((u >> 7) & 0xFF);
  int ok = (e >= 110 && e <= 132) ? 1 : 0;
  unsigned long long m = __ballot(ok);
  if ((tid & 63) == 0) cnt[tid >> 6] = __popcll(m);
  __syncthreads();
  if (tid == 0) {
    smode = (cnt[0] + cnt[1] + cnt[2] + cnt[3] > 128) ? 1 : 0;
    if (blockIdx.x == 0) {
      flag[0] = smode;
      flag[1] = 1;
    }
  }
  __syncthreads();
  int mode = smode;

  int i = blockIdx.x * 256 + tid;
  if (i < 1024) {
    // W1 fragments: 16 tiles (4 kt x 4 ct) x 64 lanes
    int tile = i >> 6, lane = i & 63;
    int kt = tile >> 2, ct = tile & 3;
#pragma unroll
    for (int j = 0; j < 8; ++j) {
      int k = kt * 32 + ((lane >> 4) << 3) + j;
      int d = (ct << 4) + (lane & 15);
      float v = ldf(W1, k * HID + d, mode);
      unsigned short h = f2bf(v);
      unsigned short l = f2bf(v - bf2f(h));
      W1hf[i * 8 + j] = h;
      W1lf[i * 8 + j] = l;
    }
  } else if (i < 1536) {
    // W2 fragments: 8 tiles (2 kt x 4 ct) x 64 lanes
    int ii = i - 1024;
    int tile = ii >> 6, lane = ii & 63;
    int kt = tile >> 2, ct = tile & 3;
#pragma unroll
    for (int j = 0; j < 8; ++j) {
      int k = kt * 32 + ((lane >> 4) << 3) + j;
      int d = (ct << 4) + (lane & 15);
      float v = ldf(W2, k * HID + d, mode);
      unsigned short h = f2bf(v);
      unsigned short l = f2bf(v - bf2f(h));
      W2hf[ii * 8 + j] = h;
      W2lf[ii * 8 + j] = l;
    }
  }
  if (i < HID) {
    b1f[i] = ldf(b1, i, mode);
    b2f[i] = ldf(b2, i, mode);
    attnWf[i] = ldf(attnW, i, mode);
  }
  if (i == 0) attnbf[0] = ldf(attnb, 0, mode);
  if (i < HID * N_CLASSES) clsWf[i] = ldf(clsW, i, mode);
  if (i < N_CLASSES) clsbf[i] = ldf(clsb, i, mode);
}

// ====== MFMA GEMM tile body: 16 nodes x 64 dims per wave =====================
// A-frag: lane holds A[lane&15][kg*8+j]. B-frag: pre-swizzled by wcvt. C/D:
// col=lane&15, row=(lane>>4)*4+reg. fp32 A -> hi/lo split (3 passes); bf16 A
// -> 2 passes (W hi/lo). SCALE fuses norm_out row scaling into the epilogue.
template <int K, bool SCALE>
__device__ __forceinline__ void gemm_tile(
    const void* __restrict__ A, const unsigned short* __restrict__ Whf,
    const unsigned short* __restrict__ Wlf, const float* __restrict__ norm_out,
    unsigned short* __restrict__ out, int mode, int mtile, int lane) {
  int n0 = mtile << 4;
  int row = lane & 15;
  int kg = lane >> 4;
  f32x4 acc0 = {0.f, 0.f, 0.f, 0.f};
  f32x4 acc1 = {0.f, 0.f, 0.f, 0.f};
  f32x4 acc2 = {0.f, 0.f, 0.f, 0.f};
  f32x4 acc3 = {0.f, 0.f, 0.f, 0.f};
  const short8v* whb0 = (const short8v*)Whf + lane;
  const short8v* wlb0 = (const short8v*)Wlf + lane;
  if (mode) {
    const unsigned short* xr = (const unsigned short*)A + (size_t)(n0 + row) * K + (kg << 3);
#pragma unroll
    for (int kt = 0; kt < K / 32; ++kt) {
      uint4 va = *(const uint4*)(xr + kt * 32);
      short8v xh = __builtin_bit_cast(short8v, va);
      const short8v* wh = whb0 + (size_t)(kt * 4) * 64;
      const short8v* wl = wlb0 + (size_t)(kt * 4) * 64;
      acc0 = mfma16(xh, wh[0], acc0);
      acc1 = mfma16(xh, wh[64], acc1);
      acc2 = mfma16(xh, wh[128], acc2);
      acc3 = mfma16(xh, wh[192], acc3);
      acc0 = mfma16(xh, wl[0], acc0);
      acc1 = mfma16(xh, wl[64], acc1);
      acc2 = mfma16(xh, wl[128], acc2);
      acc3 = mfma16(xh, wl[192], acc3);
    }
  } else {
    const float* xr = (const float*)A + (size_t)(n0 + row) * K + (kg << 3);
#pragma unroll
    for (int kt = 0; kt < K / 32; ++kt) {
      float4 a0 = *(const float4*)(xr + kt * 32);
      float4 a1 = *(const float4*)(xr + kt * 32 + 4);
      float xv[8] = {a0.x, a0.y, a0.z, a0.w, a1.x, a1.y, a1.z, a1.w};
      short8v xh, xl;
#pragma unroll
      for (int j = 0; j < 8; ++j) {
        unsigned short h = f2bf(xv[j]);
        unsigned short l = f2bf(xv[j] - bf2f(h));
        xh[j] = (short)h;
        xl[j] = (short)l;
      }
      const short8v* wh = whb0 + (size_t)(kt * 4) * 64;
      const short8v* wl = wlb0 + (size_t)(kt * 4) * 64;
      acc0 = mfma16(xh, wh[0], acc0);
      acc1 = mfma16(xh, wh[64], acc1);
      acc2 = mfma16(xh, wh[128], acc2);
      acc3 = mfma16(xh, wh[192], acc3);
      acc0 = mfma16(xh, wl[0], acc0);
      acc1 = mfma16(xh, wl[64], acc1);
      acc2 = mfma16(xh, wl[128], acc2);
      acc3 = mfma16(xh, wl[192], acc3);
      acc0 = mfma16(xl, wh[0], acc0);
      acc1 = mfma16(xl, wh[64], acc1);
      acc2 = mfma16(xl, wh[128], acc2);
      acc3 = mfma16(xl, wh[192], acc3);
    }
  }
  int col = lane & 15;
#pragma unroll
  for (int i = 0; i < 4; ++i) {
    int n = n0 + (kg << 2) + i;
    float s = SCALE ? norm_out[n] : 1.f;
    size_t rb = (size_t)n << 6;
    out[rb + col]      = f2bf(acc0[i] * s);
    out[rb + 16 + col] = f2bf(acc1[i] * s);
    out[rb + 32 + col] = f2bf(acc2[i] * s);
    out[rb + 48 + col] = f2bf(acc3[i] * s);
  }
}

// ====== FAT-A: part_count | gemm1_raw (unscaled x@W1) | gbound ===============
__global__ __launch_bounds__(256) void fatA_kernel(
    const int* __restrict__ ei, int* __restrict__ blkhistD,
    int* __restrict__ blkhistS,
    const int* __restrict__ gid, int* __restrict__ gstart,
    const void* __restrict__ x, const unsigned short* __restrict__ W1hf,
    const unsigned short* __restrict__ W1lf, unsigned short* __restrict__ bufA,
    const int* __restrict__ flag) {
  int b = (int)blockIdx.x;
  int t = (int)threadIdx.x;
  if (b < P1B) {
    __shared__ int hD[NBUCK];
    __shared__ int hS[NBUCK];
    for (int i = t; i < NBUCK; i += 256) { hD[i] = 0; hS[i] = 0; }
    __syncthreads();
    int base_e = b * EPB;
    for (int s = 0; s < EPB / 1024; ++s) {
      int e4 = base_e + s * 1024 + t * 4;
      if (e4 < N_EDGES) {
        int4 s4 = *(const int4*)(ei + e4);
        int4 d4 = *(const int4*)(ei + N_EDGES + e4);
        int ss[4] = {s4.x, s4.y, s4.z, s4.w};
        int dd[4] = {d4.x, d4.y, d4.z, d4.w};
#pragma unroll
        for (int j = 0; j < 4; ++j) {
          if ((unsigned)ss[j] < N_NODES) atomicAdd(&hS[ss[j] >> 8], 1);
          if ((unsigned)dd[j] < N_NODES) atomicAdd(&hD[dd[j] >> 8], 1);
        }
      }
    }
    __syncthreads();
    for (int i = t; i < NBUCK; i += 256) {
      blkhistD[b * NBUCK + i] = hD[i];
      blkhistS[b * NBUCK + i] = hS[i];
    }
  } else if (b < P1B + GEMM_BLOCKS) {
    int mode = flag[0];
    int mtile = (b - P1B) * 4 + (t >> 6);
    if (mtile < MTILES)
      gemm_tile<IN_DIM, false>(x, W1hf, W1lf, (const float*)0, bufA, mode,
                               mtile, t & 63);
  } else {
    // ---- gbound part ----
    int bb = b - P1B - GEMM_BLOCKS;
    int n = bb * 256 + t;
    if (n >= N_NODES) return;
    int gc = gid[n] & (N_GRAPHS - 1);
    if (n == 0) {
      for (int g = 0; g <= gc; ++g) gstart[g] = 0;
    } else {
      int gp = gid[n - 1] & (N_GRAPHS - 1);
      for (int g = gp + 1; g <= gc; ++g) gstart[g] = n;
    }
    if (n == N_NODES - 1) {
      for (int g = gc + 1; g <= N_GRAPHS; ++g) gstart[g] = N_NODES;
    }
  }
}

// =============== P2: bucket totals scan + in-place per-block bases ===========
__global__ __launch_bounds__(512) void bucket_scan_kernel(
    int* __restrict__ blkhistD, int* __restrict__ blkhistS,
    int* __restrict__ bstart_d, int* __restrict__ bstart_s) {
  int* hist = (blockIdx.x == 0) ? blkhistD : blkhistS;
  int* bst  = (blockIdx.x == 0) ? bstart_d : bstart_s;
  int u = (int)threadIdx.x;
  int tot = 0;
  if (u < NBUCK) {
    for (int blk = 0; blk < P1B; ++blk) tot += hist[blk * NBUCK + u];
  }
  __shared__ int smA[512];
  __shared__ int smB[512];
  smA[u] = tot;
  __syncthreads();
  int* a = smA;
  int* bq = smB;
  for (int off = 1; off < 512; off <<= 1) {
    int v = a[u];
    if (u >= off) v += a[u - off];
    bq[u] = v;
    __syncthreads();
    int* tmp = a; a = bq; bq = tmp;
  }
  int excl = a[u] - tot;
  if (u <= NBUCK) bst[u] = excl;  // u==NBUCK: tot==0 -> excl == total
  if (u < NBUCK) {
    int off2 = excl;
    for (int blk = 0; blk < P1B; ++blk) {
      int h = hist[blk * NBUCK + u];
      hist[blk * NBUCK + u] = off2;
      off2 += h;
    }
  }
}

// =============== P3: scatter edges into bucket-partitioned arrays ============
// edstP packs (src<<8)|(dst&255): src<2^17, dst-local<2^8 -> 25 bits.
__global__ __launch_bounds__(256) void part_scatter_kernel(
    const int* __restrict__ ei, const int* __restrict__ blkbaseD,
    const int* __restrict__ blkbaseS,
    unsigned int* __restrict__ edstP, int* __restrict__ esrc) {
  __shared__ int cD[NBUCK];
  __shared__ int cS[NBUCK];
  int b = (int)blockIdx.x;
  int t = (int)threadIdx.x;
  for (int i = t; i < NBUCK; i += 256) {
    cD[i] = blkbaseD[b * NBUCK + i];
    cS[i] = blkbaseS[b * NBUCK + i];
  }
  __syncthreads();
  int base_e = b * EPB;
  for (int s = 0; s < EPB / 1024; ++s) {
    int e4 = base_e + s * 1024 + t * 4;
    if (e4 < N_EDGES) {
      int4 s4 = *(const int4*)(ei + e4);
      int4 d4 = *(const int4*)(ei + N_EDGES + e4);
      int ss[4] = {s4.x, s4.y, s4.z, s4.w};
      int dd[4] = {d4.x, d4.y, d4.z, d4.w};
#pragma unroll
      for (int j = 0; j < 4; ++j) {
        if ((unsigned)ss[j] < N_NODES) {
          int slot = atomicAdd(&cS[ss[j] >> 8], 1);
          esrc[slot] = ss[j];
        }
        if ((unsigned)dd[j] < N_NODES) {
          int slot = atomicAdd(&cD[dd[j] >> 8], 1);
          edstP[slot] = ((unsigned int)ss[j] << 8) | ((unsigned int)dd[j] & 255u);
        }
      }
    }
  }
}

// =============== P4: per-bucket counting sort -> rowptr/col/norms ============
__global__ __launch_bounds__(256) void csr_kernel(
    const unsigned int* __restrict__ edstP, const int* __restrict__ esrc,
    const int* __restrict__ bstart_d, const int* __restrict__ bstart_s,
    int* __restrict__ rowptr, int* __restrict__ colx,
    float* __restrict__ norm_in, float* __restrict__ norm_out) {
  __shared__ int lc[256];
  __shared__ int smA[256];
  __shared__ int smB[256];
  int b = (int)blockIdx.x;
  int t = (int)threadIdx.x;
  if (b < NBUCK) {
    int node0 = b << 8;
    int base = bstart_d[b];
    int end  = bstart_d[b + 1];
    lc[t] = 0;
    __syncthreads();
    for (int i = base + t; i < end; i += 256) {
      unsigned int p = edstP[i];
      atomicAdd(&lc[p & 255u], 1);
    }
    __syncthreads();
    int my = lc[t];
    smA[t] = my;
    __syncthreads();
    int* a = smA;
    int* bq = smB;
    for (int off = 1; off < 256; off <<= 1) {
      int v = a[t];
      if (t >= off) v += a[t - off];
      bq[t] = v;
      __syncthreads();
      int* tmp = a; a = bq; bq = tmp;
    }
    int excl = a[t] - my;
    int n = node0 + t;
    if (n <= N_NODES) rowptr[n] = base + excl;
    if (n < N_NODES) {
      int c = my < 1 ? 1 : my;
      norm_in[n] = rsqrtf((float)c);
    }
    __syncthreads();
    lc[t] = base + excl;  // per-node cursor
    __syncthreads();
    for (int i = base + t; i < end; i += 256) {
      unsigned int p = edstP[i];
      int slot = atomicAdd(&lc[p & 255u], 1);
      colx[slot] = (int)(p >> 8);
    }
  } else {
    int bb = b - NBUCK;
    int node0 = bb << 8;
    int base = bstart_s[bb];
    int end  = bstart_s[bb + 1];
    lc[t] = 0;
    __syncthreads();
    for (int i = base + t; i < end; i += 256) {
      atomicAdd(&lc[esrc[i] - node0], 1);
    }
    __syncthreads();
    int n = node0 + t;
    if (n < N_NODES) {
      int c = lc[t] < 1 ? 1 : lc[t];
      norm_out[n] = rsqrtf((float)c);
    }
  }
}

// ---------------- gemm2: out = bf16((A . W) * norm_out), standalone ----------
template <int K>
__global__ __launch_bounds__(256) void gemm_mfma_kernel(
    const void* __restrict__ A, const unsigned short* __restrict__ Whf,
    const unsigned short* __restrict__ Wlf, const float* __restrict__ norm_out,
    unsigned short* __restrict__ out, const int* __restrict__ flag) {
  int mode = flag[0];
  int mtile = (int)blockIdx.x * 4 + ((int)threadIdx.x >> 6);
  if (mtile >= MTILES) return;
  gemm_tile<K, true>(A, Whf, Wlf, norm_out, out, mode, mtile,
                     (int)threadIdx.x & 63);
}

// ------- SpMM core: 8 lanes per node, serial edges, fma-scaled gather --------
__device__ __forceinline__ void accum8f(uint4 v, float no, float acc[8]) {
  float lo, hi;
  unpack_bf2(v.x, lo, hi); acc[0] = fmaf(lo, no, acc[0]); acc[1] = fmaf(hi, no, acc[1]);
  unpack_bf2(v.y, lo, hi); acc[2] = fmaf(lo, no, acc[2]); acc[3] = fmaf(hi, no, acc[3]);
  unpack_bf2(v.z, lo, hi); acc[4] = fmaf(lo, no, acc[4]); acc[5] = fmaf(hi, no, acc[5]);
  unpack_bf2(v.w, lo, hi); acc[6] = fmaf(lo, no, acc[6]); acc[7] = fmaf(hi, no, acc[7]);
}

// gather with per-src norm_out scale (v_fma == same inst count as v_add)
__device__ __forceinline__ void spmm_gather8s(const unsigned short* __restrict__ hs,
                                              const int* __restrict__ col,
                                              const float* __restrict__ no,
                                              int e0, int e1, int dim0,
                                              float acc[8]) {
  int e = e0;
  for (; e + 4 <= e1; e += 4) {
    unsigned c0 = (unsigned)col[e];
    unsigned c1 = (unsigned)col[e + 1];
    unsigned c2 = (unsigned)col[e + 2];
    unsigned c3 = (unsigned)col[e + 3];
    uint4 v0 = make_uint4(0u, 0u, 0u, 0u);
    uint4 v1 = v0, v2 = v0, v3 = v0;
    float n0 = 0.f, n1 = 0.f, n2 = 0.f, n3 = 0.f;
    if (c0 < N_NODES) { v0 = *(const uint4*)(hs + ((size_t)c0 << 6) + dim0); n0 = no[c0]; }
    if (c1 < N_NODES) { v1 = *(const uint4*)(hs + ((size_t)c1 << 6) + dim0); n1 = no[c1]; }
    if (c2 < N_NODES) { v2 = *(const uint4*)(hs + ((size_t)c2 << 6) + dim0); n2 = no[c2]; }
    if (c3 < N_NODES) { v3 = *(const uint4*)(hs + ((size_t)c3 << 6) + dim0); n3 = no[c3]; }
    accum8f(v0, n0, acc);
    accum8f(v1, n1, acc);
    accum8f(v2, n2, acc);
    accum8f(v3, n3, acc);
  }
  for (; e < e1; ++e) {
    unsigned c = (unsigned)col[e];
    uint4 v = make_uint4(0u, 0u, 0u, 0u);
    float nn = 0.f;
    if (c < N_NODES) { v = *(const uint4*)(hs + ((size_t)c << 6) + dim0); nn = no[c]; }
    accum8f(v, nn, acc);
  }
}

// plain gather (hs already scaled)
__device__ __forceinline__ void accum8(uint4 v, float acc[8]) {
  float lo, hi;
  unpack_bf2(v.x, lo, hi); acc[0] += lo; acc[1] += hi;
  unpack_bf2(v.y, lo, hi); acc[2] += lo; acc[3] += hi;
  unpack_bf2(v.z, lo, hi); acc[4] += lo; acc[5] += hi;
  unpack_bf2(v.w, lo, hi); acc[6] += lo; acc[7] += hi;
}

__device__ __forceinline__ void spmm_gather8(const unsigned short* __restrict__ hs,
                                             const int* __restrict__ col,
                                             int e0, int e1, int dim0,
                                             float acc[8]) {
  int e = e0;
  for (; e + 4 <= e1; e += 4) {
    unsigned c0 = (unsigned)col[e];
    unsigned c1 = (unsigned)col[e + 1];
    unsigned c2 = (unsigned)col[e + 2];
    unsigned c3 = (unsigned)col[e + 3];
    uint4 v0 = make_uint4(0u, 0u, 0u, 0u);
    uint4 v1 = v0, v2 = v0, v3 = v0;
    if (c0 < N_NODES) v0 = *(const uint4*)(hs + ((size_t)c0 << 6) + dim0);
    if (c1 < N_NODES) v1 = *(const uint4*)(hs + ((size_t)c1 << 6) + dim0);
    if (c2 < N_NODES) v2 = *(const uint4*)(hs + ((size_t)c2 << 6) + dim0);
    if (c3 < N_NODES) v3 = *(const uint4*)(hs + ((size_t)c3 << 6) + dim0);
    accum8(v0, acc);
    accum8(v1, acc);
    accum8(v2, acc);
    accum8(v3, acc);
  }
  for (; e < e1; ++e) {
    unsigned c = (unsigned)col[e];
    uint4 v = make_uint4(0u, 0u, 0u, 0u);
    if (c < N_NODES) v = *(const uint4*)(hs + ((size_t)c << 6) + dim0);
    accum8(v, acc);
  }
}

// ---------------- SpMM layer-1: 8 lanes per node, fma norm_out scale ---------
__global__ __launch_bounds__(256) void spmm_kernel(const unsigned short* __restrict__ hs,
                                                   const int* __restrict__ rowptr,
                                                   const int* __restrict__ col,
                                                   const float* __restrict__ norm_out,
                                                   const float* __restrict__ norm_in,
                                                   const float* __restrict__ b1f,
                                                   unsigned short* __restrict__ out) {
  int n = (int)(blockIdx.x * 32 + (threadIdx.x >> 3));
  int dim0 = ((int)threadIdx.x & 7) << 3;
  if (n >= N_NODES) return;
  int e0 = rowptr[n], e1 = rowptr[n + 1];
  if (e0 < 0) e0 = 0;
  if (e1 > N_EDGES) e1 = N_EDGES;
  float acc[8];
#pragma unroll
  for (int i = 0; i < 8; ++i) acc[i] = 0.f;
  spmm_gather8s(hs, col, norm_out, e0, e1, dim0, acc);
  float nin = norm_in[n];
  unsigned int pk[4];
#pragma unroll
  for (int i = 0; i < 4; ++i) {
    float vlo = fmaxf(acc[2 * i] * nin + b1f[dim0 + 2 * i], 0.f);
    float vhi = fmaxf(acc[2 * i + 1] * nin + b1f[dim0 + 2 * i + 1], 0.f);
    pk[i] = (unsigned int)f2bf(vlo) | ((unsigned int)f2bf(vhi) << 16);
  }
  *(uint4*)(out + ((size_t)n << 6) + dim0) = make_uint4(pk[0], pk[1], pk[2], pk[3]);
}

// ------- SpMM layer-2 fused with attention gate; 8 lanes per node ------------
__global__ __launch_bounds__(256) void spmm_attn_kernel(
    const unsigned short* __restrict__ hs,
    const int* __restrict__ rowptr, const int* __restrict__ col,
    const float* __restrict__ norm_in, const float* __restrict__ b2f,
    const float* __restrict__ attnWf, const float* __restrict__ attnbf,
    void* __restrict__ out_base, unsigned short* __restrict__ gated,
    const int* __restrict__ flag) {
  int mode = flag[0];
  int n = (int)(blockIdx.x * 32 + (threadIdx.x >> 3));
  int dim0 = ((int)threadIdx.x & 7) << 3;
  if (n >= N_NODES) return;
  int e0 = rowptr[n], e1 = rowptr[n + 1];
  if (e0 < 0) e0 = 0;
  if (e1 > N_EDGES) e1 = N_EDGES;
  float acc[8];
#pragma unroll
  for (int i = 0; i < 8; ++i) acc[i] = 0.f;
  spmm_gather8(hs, col, e0, e1, dim0, acc);
  float nin = norm_in[n];
  float vv[8];
  float p = 0.f;
#pragma unroll
  for (int i = 0; i < 8; ++i) {
    vv[i] = fmaxf(acc[i] * nin + b2f[dim0 + i], 0.f);  // h2[n][dim0+i]
    p += vv[i] * attnWf[dim0 + i];
  }
  // reduce across the 8 lanes of this node's group (lane bits 0..2)
#pragma unroll
  for (int m = 1; m <= 4; m <<= 1) p += __shfl_xor(p, m, 64);
  float logit = p + attnbf[0];
  float hwv = 1.f / (1.f + __expf(-logit));
  if ((threadIdx.x & 7) == 0) {
    if (mode) ((unsigned short*)out_base)[N_GRAPHS * N_CLASSES + n] = f2bf(hwv);
    else      ((float*)out_base)[N_GRAPHS * N_CLASSES + n] = hwv;
  }
  unsigned int pk[4];
#pragma unroll
  for (int i = 0; i < 4; ++i) {
    pk[i] = (unsigned int)f2bf(vv[2 * i] * hwv) |
            ((unsigned int)f2bf(vv[2 * i + 1] * hwv) << 16);
  }
  *(uint4*)(gated + ((size_t)n << 6) + dim0) = make_uint4(pk[0], pk[1], pk[2], pk[3]);
}

// -------- pool: 64 graphs x 32 slices, partial sums ----------
__global__ __launch_bounds__(256) void pool_kernel(const unsigned short* __restrict__ gated,
                                                   const int* __restrict__ gstart,
                                                   float* __restrict__ gpart) {
  int g = (int)blockIdx.x >> 5;         // graph
  int s = (int)blockIdx.x & 31;         // slice
  int dim = (int)threadIdx.x & 63;
  int rsel = (int)threadIdx.x >> 6;
  int r0 = gstart[g], r1 = gstart[g + 1];
  if (r0 < 0) r0 = 0;
  if (r1 > N_NODES) r1 = N_NODES;
  int len = r1 - r0;
  if (len < 0) len = 0;
  int a = r0 + (int)(((long long)len * s) >> 5);
  int bnd = r0 + (int)(((long long)len * (s + 1)) >> 5);
  float acc = 0.f;
  for (int r = a + rsel; r < bnd; r += 4)
    acc += bf2f(gated[((size_t)r << 6) + dim]);
  __shared__ float sm[256];
  sm[threadIdx.x] = acc;
  __syncthreads();
  if (threadIdx.x < 64)
    gpart[((size_t)blockIdx.x << 6) + dim] =
        sm[dim] + sm[64 + dim] + sm[128 + dim] + sm[192 + dim];
}

// ---- final (merged slice-reduce + classifier): 1 block, 640 threads ---------
__global__ __launch_bounds__(640) void final_kernel(const float* __restrict__ gpart,
                                                    const int* __restrict__ gstart,
                                                    const float* __restrict__ clsWf,
                                                    const float* __restrict__ clsbf,
                                                    void* __restrict__ out_base,
                                                    const int* __restrict__ flag) {
  __shared__ float gs[N_GRAPHS * HID];
  int t = (int)threadIdx.x;
  for (int idx = t; idx < N_GRAPHS * HID; idx += 640) {
    int g = idx >> 6, d = idx & 63;
    float a = 0.f;
#pragma unroll
    for (int s = 0; s < POOL_SLICES; ++s)
      a += gpart[(((size_t)(g << 5) + s) << 6) + d];
    gs[idx] = a;
  }
  __syncthreads();
  int mode = flag[0];
  if (t >= N_GRAPHS * N_CLASSES) return;
  int g = t / N_CLASSES, c = t - g * N_CLASSES;
  int cg = gstart[g + 1] - gstart[g];
  if (cg < 1) cg = 1;
  float inv = 1.f / (float)cg;
  float acc = 0.f;
#pragma unroll
  for (int d = 0; d < HID; ++d) acc += gs[(g << 6) + d] * clsWf[d * N_CLASSES + c];
  float r = acc * inv + clsbf[c];
  if (mode) ((unsigned short*)out_base)[t] = f2bf(r);
  else      ((float*)out_base)[t] = r;
}

extern "C" void kernel_launch(void* const* d_in, const int* in_sizes, int n_in,
                              void* d_out, int out_size, void* d_ws, size_t ws_size,
                              hipStream_t stream) {
  const void* x     = d_in[0];
  const int*  ei    = (const int*)d_in[1];
  const int*  gid   = (const int*)d_in[2];
  const void* W1    = d_in[3];
  const void* b1    = d_in[4];
  const void* W2    = d_in[5];
  const void* b2    = d_in[6];
  const void* attnW = d_in[7];
  const void* attnb = d_in[8];
  const void* clsW  = d_in[9];
  const void* clsb  = d_in[10];

  if (ws_size < (size_t)WS_NEED) {
    fallback_kernel<<<(out_size + 255) / 256, 256, 0, stream>>>(
        (unsigned short*)d_out, out_size);
    return;
  }

  // ---- workspace layout (bytes). Every buffer fully written by a producer. ----
  char* w = (char*)d_ws;
  int*   flag     = (int*)(w + 0);          //      64 (2 used, wcvt writes)
  int*   gstart   = (int*)(w + 64);         //     512 (gbound writes all)
  float* gsum_un  = (float*)(w + 576);      //   16384 (unused; kept for layout)
  int*   bstart_d = (int*)(w + 16960);      //    1600 (392 used)
  int*   bstart_s = (int*)(w + 18560);      //    1600
  int*   blkhD    = (int*)(w + 20160);      //  306560 (196*391 ints)
  int*   blkhS    = (int*)(w + 326720);     //  306560
  int*   rowptr   = (int*)(w + 633280);     //  400064 (100001 used)
  float* norm_out = (float*)(w + 1033344);  //  400000
  float* norm_in  = (float*)(w + 1433344);  //  400000
  unsigned short* W1hf = (unsigned short*)(w + 1833344);  // 16384
  unsigned short* W1lf = (unsigned short*)(w + 1849728);  // 16384
  unsigned short* W2hf = (unsigned short*)(w + 1866112);  //  8192
  unsigned short* W2lf = (unsigned short*)(w + 1874304);  //  8192 -> 1882496
  float* b1f      = (float*)(w + 1882496);  //     256
  float* b2f      = (float*)(w + 1882752);  //     256
  float* attnWf   = (float*)(w + 1883008);  //     256
  float* attnbf   = (float*)(w + 1883264);  //      64
  float* clsWf    = (float*)(w + 1883328);  //    2560
  float* clsbf    = (float*)(w + 1885888);  //      64 -> 1885952
  int*   colx     = (int*)(w + 1885952);    //  6400000 -> 8285952
  unsigned int* edstP = (unsigned int*)(w + 8285952);   // 6400000 -> 14685952
  int*   esrc     = (int*)(w + 14685952);   //  6400000 -> 21085952
  unsigned short* bufA = (unsigned short*)(w + 21085952); // 12800000 -> 33885952
  // bufB aliases edstP+esrc (dead after csr; spmm1 writes after csr).
  unsigned short* bufB = (unsigned short*)(w + 8285952);  // 12800000
  // gpart aliases blkhD/S (dead after part_scatter consumes the bases).
  float* gpart    = (float*)(w + 20160);    // 524288 <= 613120 available
  (void)gsum_un;

  // wcvt self-probes x's dtype and writes flag; converts weights to fragments.
  wcvt_kernel<<<32, 256, 0, stream>>>((const unsigned short*)x, W1, W2, b1, b2,
                                      attnW, attnb, clsW, clsb, W1hf, W1lf,
                                      W2hf, W2lf, b1f, b2f, attnWf, attnbf,
                                      clsWf, clsbf, flag);

  // FAT-A: bucket histograms | gemm1_raw (unscaled x@W1, MFMA) | graph bounds
  fatA_kernel<<<P1B + GEMM_BLOCKS + GB_BLOCKS, 256, 0, stream>>>(
      ei, blkhD, blkhS, gid, gstart, x, W1hf, W1lf, bufA, flag);

  bucket_scan_kernel<<<2, 512, 0, stream>>>(blkhD, blkhS, bstart_d, bstart_s);
  part_scatter_kernel<<<P1B, 256, 0, stream>>>(ei, blkhD, blkhS, edstP, esrc);
  csr_kernel<<<2 * NBUCK, 256, 0, stream>>>(edstP, esrc, bstart_d, bstart_s,
                                            rowptr, colx, norm_in, norm_out);

  // layer 1 aggregation: h1 = relu((Agg hs1raw[src]*norm_out[src])*norm_in+b1)
  spmm_kernel<<<SPMM_BLOCKS, 256, 0, stream>>>(bufA, rowptr, colx, norm_out,
                                               norm_in, b1f, bufB);

  // layer 2: hs2 = (h1 @ W2) * norm_out (MFMA; input bf16 via flag+1)
  gemm_mfma_kernel<HID><<<GEMM_BLOCKS, 256, 0, stream>>>(
      bufB, W2hf, W2lf, norm_out, bufA, flag + 1);
  spmm_attn_kernel<<<SPMM_BLOCKS, 256, 0, stream>>>(
      bufA, rowptr, colx, norm_in, b2f, attnWf, attnbf, d_out, bufB, flag);

  // pooling: 2048 slice blocks -> partials; final merges reduce + classifier
  pool_kernel<<<N_GRAPHS * POOL_SLICES, 256, 0, stream>>>(bufB, gstart, gpart);
  final_kernel<<<1, 640, 0, stream>>>(gpart, gstart, clsWf, clsbf, d_out, flag);
}